// Round 1
// baseline (5587.709 us; speedup 1.0000x reference)
//
#include <hip/hip_runtime.h>

#define THREADS 256

// ---------------------------------------------------------------------------
// k_degrees: count out-degree (src) and in-degree (dst) with int atomics.
// ---------------------------------------------------------------------------
__global__ void k_degrees(const int* __restrict__ src, const int* __restrict__ dst,
                          int* __restrict__ deg_out, int* __restrict__ deg_in, int nE) {
    int e = blockIdx.x * blockDim.x + threadIdx.x;
    if (e < nE) {
        atomicAdd(&deg_out[src[e]], 1);
        atomicAdd(&deg_in[dst[e]], 1);
    }
}

// ---------------------------------------------------------------------------
// k_scale: rsq_out/rsq_in = rsqrt(max(deg,1)); xs = x * rsq_out (per node).
// ---------------------------------------------------------------------------
__global__ void k_scale(const float* __restrict__ x,
                        const int* __restrict__ deg_out, const int* __restrict__ deg_in,
                        float* __restrict__ rsq_out, float* __restrict__ rsq_in,
                        float* __restrict__ xs, int nN) {
    int n = blockIdx.x * blockDim.x + threadIdx.x;
    if (n >= nN) return;
    int dn_o = deg_out[n], dn_i = deg_in[n];
    float ro = rsqrtf((float)(dn_o > 1 ? dn_o : 1));
    float ri = rsqrtf((float)(dn_i > 1 ? dn_i : 1));
    rsq_out[n] = ro;
    rsq_in[n]  = ri;
    const float4* x4 = (const float4*)(x + (size_t)n * 16);
    float4* xs4 = (float4*)(xs + (size_t)n * 16);
#pragma unroll
    for (int k = 0; k < 4; ++k) {
        float4 v = x4[k];
        v.x *= ro; v.y *= ro; v.z *= ro; v.w *= ro;
        xs4[k] = v;
    }
}

// ---------------------------------------------------------------------------
// k_agg: for each edge, agg[dst] += feat[src] (16 f32 per edge).
// One thread per edge: 4x float4 gather + 16 HW f32 atomics.
// ---------------------------------------------------------------------------
__global__ void k_agg(const int* __restrict__ src, const int* __restrict__ dst,
                      const float* __restrict__ feat, float* __restrict__ agg, int nE) {
    int e = blockIdx.x * blockDim.x + threadIdx.x;
    if (e >= nE) return;
    int s = src[e], d = dst[e];
    const float4* f4 = (const float4*)(feat + (size_t)s * 16);
    float* a = agg + (size_t)d * 16;
#pragma unroll
    for (int k = 0; k < 4; ++k) {
        float4 v = f4[k];
        unsafeAtomicAdd(a + 4 * k + 0, v.x);
        unsafeAtomicAdd(a + 4 * k + 1, v.y);
        unsafeAtomicAdd(a + 4 * k + 2, v.z);
        unsafeAtomicAdd(a + 4 * k + 3, v.w);
    }
}

// ---------------------------------------------------------------------------
// k_mlp: per node:
//   t = agg1[n] * rsq_in[n]            (layer-1 dst norm)
//   y = tanh(t @ W1 + b1)              [64]
//   z = (y @ W2) * rsq_out[n]          (W2 hoisted BEFORE layer-2 aggregation)
// Weights indexed wave-uniformly -> s_load + SGPR-operand FMA expected.
// ---------------------------------------------------------------------------
__global__ __launch_bounds__(THREADS) void k_mlp(
    const float* __restrict__ agg1, const float* __restrict__ rsq_in,
    const float* __restrict__ rsq_out, const float* __restrict__ w1,
    const float* __restrict__ b1, const float* __restrict__ w2,
    float* __restrict__ z, int nN)
{
    int n = blockIdx.x * blockDim.x + threadIdx.x;
    if (n >= nN) return;
    float ri = rsq_in[n];
    const float4* a4 = (const float4*)(agg1 + (size_t)n * 16);
    float t[16];
#pragma unroll
    for (int k = 0; k < 4; ++k) {
        float4 v = a4[k];
        t[4 * k + 0] = v.x * ri; t[4 * k + 1] = v.y * ri;
        t[4 * k + 2] = v.z * ri; t[4 * k + 3] = v.w * ri;
    }
    float y[64];
#pragma unroll
    for (int j = 0; j < 64; ++j) y[j] = b1[j];
    // y += t @ W1  — iterate i outer so w1 row (64 contiguous floats) is uniform
#pragma unroll
    for (int i = 0; i < 16; ++i) {
        float ti = t[i];
#pragma unroll
        for (int j = 0; j < 64; ++j) y[j] = fmaf(ti, w1[i * 64 + j], y[j]);
    }
#pragma unroll
    for (int j = 0; j < 64; ++j) y[j] = tanhf(y[j]);
    float u[16];
#pragma unroll
    for (int o = 0; o < 16; ++o) u[o] = 0.0f;
#pragma unroll
    for (int j = 0; j < 64; ++j) {
        float yj = y[j];
#pragma unroll
        for (int o = 0; o < 16; ++o) u[o] = fmaf(yj, w2[j * 16 + o], u[o]);
    }
    float ro = rsq_out[n];
    float4* z4 = (float4*)(z + (size_t)n * 16);
#pragma unroll
    for (int k = 0; k < 4; ++k) {
        z4[k] = make_float4(u[4 * k + 0] * ro, u[4 * k + 1] * ro,
                            u[4 * k + 2] * ro, u[4 * k + 3] * ro);
    }
}

// ---------------------------------------------------------------------------
// k_out: g = agg2 * rsq_in + b2; out = g @ J^T  (pure permute/negate):
//   out[i] = g[i+8]  (i<8);  out[i] = -g[i-8]  (i>=8)
// ---------------------------------------------------------------------------
__global__ void k_out(const float* __restrict__ agg2, const float* __restrict__ rsq_in,
                      const float* __restrict__ b2, float* __restrict__ out, int nN) {
    int n = blockIdx.x * blockDim.x + threadIdx.x;
    if (n >= nN) return;
    float ri = rsq_in[n];
    const float4* a4 = (const float4*)(agg2 + (size_t)n * 16);
    float g[16];
#pragma unroll
    for (int k = 0; k < 4; ++k) {
        float4 v = a4[k];
        g[4 * k + 0] = fmaf(v.x, ri, b2[4 * k + 0]);
        g[4 * k + 1] = fmaf(v.y, ri, b2[4 * k + 1]);
        g[4 * k + 2] = fmaf(v.z, ri, b2[4 * k + 2]);
        g[4 * k + 3] = fmaf(v.w, ri, b2[4 * k + 3]);
    }
    float4* o4 = (float4*)(out + (size_t)n * 16);
    o4[0] = make_float4( g[8],  g[9],  g[10],  g[11]);
    o4[1] = make_float4( g[12], g[13], g[14],  g[15]);
    o4[2] = make_float4(-g[0], -g[1], -g[2],  -g[3]);
    o4[3] = make_float4(-g[4], -g[5], -g[6],  -g[7]);
}

extern "C" void kernel_launch(void* const* d_in, const int* in_sizes, int n_in,
                              void* d_out, int out_size, void* d_ws, size_t ws_size,
                              hipStream_t stream) {
    const float* x  = (const float*)d_in[0];
    const int*   src = (const int*)d_in[1];
    const int*   dst = (const int*)d_in[2];
    const float* w1 = (const float*)d_in[3];
    const float* b1 = (const float*)d_in[4];
    const float* w2 = (const float*)d_in[5];
    const float* b2 = (const float*)d_in[6];
    float* out = (float*)d_out;

    const int nN = in_sizes[0] / 16;
    const int nE = in_sizes[1];

    // Workspace carve-up (256B aligned). Total ~15 MB.
    char* ws = (char*)d_ws;
    size_t off = 0;
    auto carve = [&](size_t bytes) -> void* {
        void* p = ws + off;
        off += (bytes + 255) & ~(size_t)255;
        return p;
    };
    int*   deg     = (int*)  carve((size_t)2 * nN * sizeof(int));   // deg_out | deg_in
    int*   deg_out = deg;
    int*   deg_in  = deg + nN;
    float* rsq_out = (float*)carve((size_t)nN * sizeof(float));
    float* rsq_in  = (float*)carve((size_t)nN * sizeof(float));
    float* xs      = (float*)carve((size_t)nN * 16 * sizeof(float)); // x_scaled, later z
    float* agg     = (float*)carve((size_t)nN * 16 * sizeof(float)); // agg1, later agg2

    const int edge_blocks = (nE + THREADS - 1) / THREADS;
    const int node_blocks = (nN + THREADS - 1) / THREADS;

    // 1. degrees
    hipMemsetAsync(deg, 0, (size_t)2 * nN * sizeof(int), stream);
    k_degrees<<<edge_blocks, THREADS, 0, stream>>>(src, dst, deg_out, deg_in, nE);

    // 2. norms + pre-scaled x
    k_scale<<<node_blocks, THREADS, 0, stream>>>(x, deg_out, deg_in, rsq_out, rsq_in, xs, nN);

    // 3. layer-1 aggregation (16 f32/edge)
    hipMemsetAsync(agg, 0, (size_t)nN * 16 * sizeof(float), stream);
    k_agg<<<edge_blocks, THREADS, 0, stream>>>(src, dst, xs, agg, nE);

    // 4. fused MLP: tanh(agg*ri @ W1 + b1) @ W2 * ro  -> z (reuses xs buffer)
    k_mlp<<<node_blocks, THREADS, 0, stream>>>(agg, rsq_in, rsq_out, w1, b1, w2, xs, nN);

    // 5. layer-2 aggregation (16 f32/edge thanks to hoisted W2)
    hipMemsetAsync(agg, 0, (size_t)nN * 16 * sizeof(float), stream);
    k_agg<<<edge_blocks, THREADS, 0, stream>>>(src, dst, xs, agg, nE);

    // 6. epilogue: dst norm + b2 + symplectic permute
    k_out<<<node_blocks, THREADS, 0, stream>>>(agg, rsq_in, b2, out, nN);
}

// Round 4
// 780.238 us; speedup vs baseline: 7.1615x; 7.1615x over previous
//
#include <hip/hip_runtime.h>

#define THREADS 256

// ---------------------------------------------------------------------------
// k_degrees: out-degree (src) / in-degree (dst) via int atomics.
// ---------------------------------------------------------------------------
__global__ void k_degrees(const int* __restrict__ src, const int* __restrict__ dst,
                          int* __restrict__ deg_out, int* __restrict__ deg_in, int nE) {
    int e = blockIdx.x * blockDim.x + threadIdx.x;
    if (e < nE) {
        atomicAdd(&deg_out[src[e]], 1);
        atomicAdd(&deg_in[dst[e]], 1);
    }
}

// ---------------------------------------------------------------------------
// k_prep: per node n:
//   rsq_out/rsq_in = rsqrt(max(deg,1)); xs = x * rsq_out
//   row_start[n] via wave-level exclusive scan of deg_in + one atomicAdd/wave
//   cursor[n] = row_start[n]  (bump-allocated by k_bin)
// Whole wave participates in the scan (invalid lanes contribute 0).
// ---------------------------------------------------------------------------
__global__ void k_prep(const float* __restrict__ x,
                       const int* __restrict__ deg_out, const int* __restrict__ deg_in,
                       float* __restrict__ rsq_out, float* __restrict__ rsq_in,
                       float* __restrict__ xs, int* __restrict__ row_start,
                       int* __restrict__ cursor, unsigned int* __restrict__ alloc, int nN) {
    int n = blockIdx.x * blockDim.x + threadIdx.x;
    int lane = threadIdx.x & 63;
    bool valid = (n < nN);
    int di = valid ? deg_in[n] : 0;

    // inclusive wave scan of di
    int incl = di;
#pragma unroll
    for (int off = 1; off < 64; off <<= 1) {
        int v = __shfl_up(incl, off, 64);
        if (lane >= off) incl += v;
    }
    int excl = incl - di;
    int total = __shfl(incl, 63, 64);
    int base = 0;
    if (lane == 0) base = (int)atomicAdd(alloc, (unsigned int)total);
    base = __shfl(base, 0, 64);

    if (valid) {
        int rs = base + excl;
        row_start[n] = rs;
        cursor[n] = rs;
        int dn_o = deg_out[n];
        float ro = rsqrtf((float)(dn_o > 1 ? dn_o : 1));
        float ri = rsqrtf((float)(di > 1 ? di : 1));
        rsq_out[n] = ro;
        rsq_in[n] = ri;
        const float4* x4 = (const float4*)(x + (size_t)n * 16);
        float4* xs4 = (float4*)(xs + (size_t)n * 16);
#pragma unroll
        for (int k = 0; k < 4; ++k) {
            float4 v = x4[k];
            v.x *= ro; v.y *= ro; v.z *= ro; v.w *= ro;
            xs4[k] = v;
        }
    }
}

// ---------------------------------------------------------------------------
// k_bin: scatter edges into dst-grouped CSR (src ids). 3.2M int atomics.
// ---------------------------------------------------------------------------
__global__ void k_bin(const int* __restrict__ src, const int* __restrict__ dst,
                      int* __restrict__ cursor, int* __restrict__ csr_src, int nE) {
    int e = blockIdx.x * blockDim.x + threadIdx.x;
    if (e < nE) {
        int d = dst[e];
        int pos = atomicAdd(&cursor[d], 1);
        csr_src[pos] = src[e];
    }
}

// ---------------------------------------------------------------------------
// k_agg1: gather-side aggregation, 4 lanes per node (one float4 slice each).
// The 4 lanes' 16B loads of one src row coalesce into a single 64B request.
// Register accumulation — zero f32 atomics, no output memset needed.
// Unroll-4: keep 4 independent loads in flight to hide miss latency.
// ---------------------------------------------------------------------------
__global__ void k_agg1(const int* __restrict__ row_start, const int* __restrict__ deg_in,
                       const int* __restrict__ csr_src, const float* __restrict__ feat,
                       float* __restrict__ agg, int nN) {
    int tid = blockIdx.x * blockDim.x + threadIdx.x;
    int n = tid >> 2, q = tid & 3;
    if (n >= nN) return;
    int row = row_start[n], deg = deg_in[n];
    const float* fb = feat + q * 4;
    float4 acc = make_float4(0.f, 0.f, 0.f, 0.f);
    int i = 0;
    for (; i + 4 <= deg; i += 4) {
        int s0 = csr_src[row + i];
        int s1 = csr_src[row + i + 1];
        int s2 = csr_src[row + i + 2];
        int s3 = csr_src[row + i + 3];
        float4 v0 = *(const float4*)(fb + (size_t)s0 * 16);
        float4 v1 = *(const float4*)(fb + (size_t)s1 * 16);
        float4 v2 = *(const float4*)(fb + (size_t)s2 * 16);
        float4 v3 = *(const float4*)(fb + (size_t)s3 * 16);
        acc.x += v0.x + v1.x + v2.x + v3.x;
        acc.y += v0.y + v1.y + v2.y + v3.y;
        acc.z += v0.z + v1.z + v2.z + v3.z;
        acc.w += v0.w + v1.w + v2.w + v3.w;
    }
    for (; i < deg; ++i) {
        int s0 = csr_src[row + i];
        float4 v0 = *(const float4*)(fb + (size_t)s0 * 16);
        acc.x += v0.x; acc.y += v0.y; acc.z += v0.z; acc.w += v0.w;
    }
    ((float4*)agg)[(size_t)n * 4 + q] = acc;
}

// ---------------------------------------------------------------------------
// k_mlp: chunked so the live set stays ~48 floats (no scratch demotion):
//   t = agg1*ri; for each 16-wide chunk c of hidden dim:
//     yv = tanh(t @ W1[:,c] + b1[c]);  u += yv @ W2[c,:]
//   z = u * ro
// ---------------------------------------------------------------------------
__global__ __launch_bounds__(THREADS) void k_mlp(
    const float* __restrict__ agg1, const float* __restrict__ rsq_in,
    const float* __restrict__ rsq_out, const float* __restrict__ w1,
    const float* __restrict__ b1, const float* __restrict__ w2,
    float* __restrict__ z, int nN)
{
    int n = blockIdx.x * blockDim.x + threadIdx.x;
    if (n >= nN) return;
    float ri = rsq_in[n];
    const float4* a4 = (const float4*)(agg1 + (size_t)n * 16);
    float t[16];
#pragma unroll
    for (int k = 0; k < 4; ++k) {
        float4 v = a4[k];
        t[4*k+0] = v.x * ri; t[4*k+1] = v.y * ri;
        t[4*k+2] = v.z * ri; t[4*k+3] = v.w * ri;
    }
    float u[16];
#pragma unroll
    for (int o = 0; o < 16; ++o) u[o] = 0.f;
#pragma unroll
    for (int c = 0; c < 4; ++c) {
        float yv[16];
#pragma unroll
        for (int jj = 0; jj < 16; ++jj) yv[jj] = b1[c*16 + jj];
#pragma unroll
        for (int i = 0; i < 16; ++i) {
            float ti = t[i];
#pragma unroll
            for (int jj = 0; jj < 16; ++jj)
                yv[jj] = fmaf(ti, w1[i*64 + c*16 + jj], yv[jj]);
        }
#pragma unroll
        for (int jj = 0; jj < 16; ++jj) yv[jj] = tanhf(yv[jj]);
#pragma unroll
        for (int jj = 0; jj < 16; ++jj) {
            float yj = yv[jj];
#pragma unroll
            for (int o = 0; o < 16; ++o)
                u[o] = fmaf(yj, w2[(c*16 + jj)*16 + o], u[o]);
        }
    }
    float ro = rsq_out[n];
    float4* z4 = (float4*)(z + (size_t)n * 16);
#pragma unroll
    for (int k = 0; k < 4; ++k)
        z4[k] = make_float4(u[4*k+0]*ro, u[4*k+1]*ro, u[4*k+2]*ro, u[4*k+3]*ro);
}

// ---------------------------------------------------------------------------
// k_agg2: same gather structure, fused epilogue:
//   g = acc*ri + b2;  out = g @ J^T via quad-lane shfl_xor(2) + sign.
//   out quad q = (q<2 ? + : -) g from quad (q^2).
// ---------------------------------------------------------------------------
__global__ void k_agg2(const int* __restrict__ row_start, const int* __restrict__ deg_in,
                       const int* __restrict__ csr_src, const float* __restrict__ feat,
                       const float* __restrict__ rsq_in, const float* __restrict__ b2,
                       float* __restrict__ out, int nN) {
    int tid = blockIdx.x * blockDim.x + threadIdx.x;
    int n = tid >> 2, q = tid & 3;
    if (n >= nN) return;
    int row = row_start[n], deg = deg_in[n];
    const float* fb = feat + q * 4;
    float4 acc = make_float4(0.f, 0.f, 0.f, 0.f);
    int i = 0;
    for (; i + 4 <= deg; i += 4) {
        int s0 = csr_src[row + i];
        int s1 = csr_src[row + i + 1];
        int s2 = csr_src[row + i + 2];
        int s3 = csr_src[row + i + 3];
        float4 v0 = *(const float4*)(fb + (size_t)s0 * 16);
        float4 v1 = *(const float4*)(fb + (size_t)s1 * 16);
        float4 v2 = *(const float4*)(fb + (size_t)s2 * 16);
        float4 v3 = *(const float4*)(fb + (size_t)s3 * 16);
        acc.x += v0.x + v1.x + v2.x + v3.x;
        acc.y += v0.y + v1.y + v2.y + v3.y;
        acc.z += v0.z + v1.z + v2.z + v3.z;
        acc.w += v0.w + v1.w + v2.w + v3.w;
    }
    for (; i < deg; ++i) {
        int s0 = csr_src[row + i];
        float4 v0 = *(const float4*)(fb + (size_t)s0 * 16);
        acc.x += v0.x; acc.y += v0.y; acc.z += v0.z; acc.w += v0.w;
    }
    float ri = rsq_in[n];
    float4 bq = *(const float4*)(b2 + q * 4);
    float4 g = make_float4(fmaf(acc.x, ri, bq.x), fmaf(acc.y, ri, bq.y),
                           fmaf(acc.z, ri, bq.z), fmaf(acc.w, ri, bq.w));
    // symplectic permute across quads: partner quad = q ^ 2
    float4 p;
    p.x = __shfl_xor(g.x, 2, 64);
    p.y = __shfl_xor(g.y, 2, 64);
    p.z = __shfl_xor(g.z, 2, 64);
    p.w = __shfl_xor(g.w, 2, 64);
    float sgn = (q < 2) ? 1.f : -1.f;
    ((float4*)out)[(size_t)n * 4 + q] =
        make_float4(sgn * p.x, sgn * p.y, sgn * p.z, sgn * p.w);
}

extern "C" void kernel_launch(void* const* d_in, const int* in_sizes, int n_in,
                              void* d_out, int out_size, void* d_ws, size_t ws_size,
                              hipStream_t stream) {
    const float* x  = (const float*)d_in[0];
    const int*   src = (const int*)d_in[1];
    const int*   dst = (const int*)d_in[2];
    const float* w1 = (const float*)d_in[3];
    const float* b1 = (const float*)d_in[4];
    const float* w2 = (const float*)d_in[5];
    const float* b2 = (const float*)d_in[6];
    float* out = (float*)d_out;

    const int nN = in_sizes[0] / 16;
    const int nE = in_sizes[1];

    // Workspace carve-up (256B aligned). Total ~28 MB.
    char* ws = (char*)d_ws;
    size_t off = 0;
    auto carve = [&](size_t bytes) -> void* {
        void* p = ws + off;
        off += (bytes + 255) & ~(size_t)255;
        return p;
    };
    // [deg_out | deg_in | alloc] contiguous -> single memset
    int* deg = (int*)carve(((size_t)2 * nN + 64) * sizeof(int));
    int* deg_out = deg;
    int* deg_in  = deg + nN;
    unsigned int* alloc = (unsigned int*)(deg + 2 * nN);
    float* rsq_out  = (float*)carve((size_t)nN * sizeof(float));
    float* rsq_in   = (float*)carve((size_t)nN * sizeof(float));
    int*   row_start = (int*)carve((size_t)nN * sizeof(int));
    int*   cursor    = (int*)carve((size_t)nN * sizeof(int));
    float* xs   = (float*)carve((size_t)nN * 16 * sizeof(float)); // xs, later z
    float* agg1 = (float*)carve((size_t)nN * 16 * sizeof(float));
    int*   csr_src = (int*)carve((size_t)nE * sizeof(int));

    const int edge_blocks = (nE + THREADS - 1) / THREADS;
    const int node_blocks = (nN + THREADS - 1) / THREADS;
    const int quad_blocks = (4 * nN + THREADS - 1) / THREADS;

    // 1. zero degree tables + allocator
    hipMemsetAsync(deg, 0, ((size_t)2 * nN + 64) * sizeof(int), stream);
    // 2. degrees
    k_degrees<<<edge_blocks, THREADS, 0, stream>>>(src, dst, deg_out, deg_in, nE);
    // 3. norms + xs + CSR row offsets
    k_prep<<<node_blocks, THREADS, 0, stream>>>(x, deg_out, deg_in, rsq_out, rsq_in,
                                                xs, row_start, cursor, alloc, nN);
    // 4. bin edges into CSR (src ids grouped by dst)
    k_bin<<<edge_blocks, THREADS, 0, stream>>>(src, dst, cursor, csr_src, nE);
    // 5. layer-1 aggregation (gather-side, register accumulate)
    k_agg1<<<quad_blocks, THREADS, 0, stream>>>(row_start, deg_in, csr_src, xs, agg1, nN);
    // 6. fused MLP (W2 hoisted before layer-2 aggregation); writes z into xs
    k_mlp<<<node_blocks, THREADS, 0, stream>>>(agg1, rsq_in, rsq_out, w1, b1, w2, xs, nN);
    // 7. layer-2 aggregation + fused epilogue (ri, b2, symplectic permute)
    k_agg2<<<quad_blocks, THREADS, 0, stream>>>(row_start, deg_in, csr_src, xs,
                                                rsq_in, b2, out, nN);
}

// Round 5
// 645.430 us; speedup vs baseline: 8.6573x; 1.2089x over previous
//
#include <hip/hip_runtime.h>

#define THREADS 256
#define NB_MAX 512      // max bucket count (hist arrays sized to this)
#define BATCH 4096      // edges per k_bucketA block

// ---------------------------------------------------------------------------
// k_degrees: out/in degree atomics + LDS-staged bucket histogram of dst>>shift.
// Grid-stride with ~1024 blocks so the histogram flush is only ~400k atomics.
// ---------------------------------------------------------------------------
__global__ void k_degrees(const int* __restrict__ src, const int* __restrict__ dst,
                          int* __restrict__ deg_out, int* __restrict__ deg_in,
                          int* __restrict__ bucket_cnt, int shift, int nE) {
    __shared__ int hist[NB_MAX];
    for (int i = threadIdx.x; i < NB_MAX; i += THREADS) hist[i] = 0;
    __syncthreads();
    int stride = gridDim.x * blockDim.x;
    for (int e = blockIdx.x * blockDim.x + threadIdx.x; e < nE; e += stride) {
        atomicAdd(&deg_out[src[e]], 1);
        int d = dst[e];
        atomicAdd(&deg_in[d], 1);
        atomicAdd(&hist[d >> shift], 1);
    }
    __syncthreads();
    for (int i = threadIdx.x; i < NB_MAX; i += THREADS) {
        int c = hist[i];
        if (c) atomicAdd(&bucket_cnt[i], c);
    }
}

// ---------------------------------------------------------------------------
// k_bscan: single block. Exclusive scan of bucket_cnt[0..NB_MAX) ->
// bucket_base, and init bucket_cursor = base. Thread t owns entries 2t,2t+1.
// ---------------------------------------------------------------------------
__global__ void k_bscan(const int* __restrict__ bucket_cnt,
                        int* __restrict__ bucket_base, int* __restrict__ bucket_cursor) {
    __shared__ int wsum[4];
    int t = threadIdx.x;
    int lane = t & 63, wid = t >> 6;
    int h0 = bucket_cnt[2 * t], h1 = bucket_cnt[2 * t + 1];
    int s = h0 + h1;
    int incl = s;
#pragma unroll
    for (int off = 1; off < 64; off <<= 1) {
        int v = __shfl_up(incl, off, 64);
        if (lane >= off) incl += v;
    }
    if (lane == 63) wsum[wid] = incl;
    __syncthreads();
    int woff = 0;
    for (int w = 0; w < wid; ++w) woff += wsum[w];
    int excl = woff + incl - s;
    bucket_base[2 * t] = excl;
    bucket_base[2 * t + 1] = excl + h0;
    bucket_cursor[2 * t] = excl;
    bucket_cursor[2 * t + 1] = excl + h0;
}

// ---------------------------------------------------------------------------
// k_prep: rsqrt norms, xs = x*ro, CSR row_start via wave scan of deg_in,
// cursor init. (unchanged from prior round)
// ---------------------------------------------------------------------------
__global__ void k_prep(const float* __restrict__ x,
                       const int* __restrict__ deg_out, const int* __restrict__ deg_in,
                       float* __restrict__ rsq_out, float* __restrict__ rsq_in,
                       float* __restrict__ xs, int* __restrict__ row_start,
                       int* __restrict__ cursor, unsigned int* __restrict__ alloc, int nN) {
    int n = blockIdx.x * blockDim.x + threadIdx.x;
    int lane = threadIdx.x & 63;
    bool valid = (n < nN);
    int di = valid ? deg_in[n] : 0;
    int incl = di;
#pragma unroll
    for (int off = 1; off < 64; off <<= 1) {
        int v = __shfl_up(incl, off, 64);
        if (lane >= off) incl += v;
    }
    int excl = incl - di;
    int total = __shfl(incl, 63, 64);
    int base = 0;
    if (lane == 0) base = (int)atomicAdd(alloc, (unsigned int)total);
    base = __shfl(base, 0, 64);
    if (valid) {
        int rs = base + excl;
        row_start[n] = rs;
        cursor[n] = rs;
        int dn_o = deg_out[n];
        float ro = rsqrtf((float)(dn_o > 1 ? dn_o : 1));
        float ri = rsqrtf((float)(di > 1 ? di : 1));
        rsq_out[n] = ro;
        rsq_in[n] = ri;
        const float4* x4 = (const float4*)(x + (size_t)n * 16);
        float4* xs4 = (float4*)(xs + (size_t)n * 16);
#pragma unroll
        for (int k = 0; k < 4; ++k) {
            float4 v = x4[k];
            v.x *= ro; v.y *= ro; v.z *= ro; v.w *= ro;
            xs4[k] = v;
        }
    }
}

// ---------------------------------------------------------------------------
// k_bucketA: block counting-sort of a 4096-edge batch by bucket (dst>>shift),
// then flush contiguous per-bucket runs to the global pairs[] array at
// positions reserved with ONE atomicAdd per (block,bucket). Writes are
// contiguous runs (~10 edges) instead of random 4B -> kills write-amp.
// Edge packed to 4B: (src << shift) | (dst & ((1<<shift)-1)).
// Valid while nN <= 2^(32-shift) (here nN=100k, shift=8 -> 16.7M cap).
// ---------------------------------------------------------------------------
__global__ __launch_bounds__(THREADS) void k_bucketA(
    const int* __restrict__ src, const int* __restrict__ dst,
    int* __restrict__ bucket_cursor, unsigned int* __restrict__ pairs,
    int shift, int nE)
{
    __shared__ int base[NB_MAX];   // hist, then scanned exclusive bases
    __shared__ int cnt2[NB_MAX];
    __shared__ int gbase[NB_MAX];
    __shared__ int wsum[4];
    __shared__ unsigned int st[BATCH];
    int t = threadIdx.x;
    int bstart = blockIdx.x * BATCH;
    int bcount = min(BATCH, nE - bstart);
    unsigned int lmask = (1u << shift) - 1u;

    for (int i = t; i < NB_MAX; i += THREADS) { base[i] = 0; cnt2[i] = 0; }
    __syncthreads();
    // pass 1: histogram
#pragma unroll
    for (int i = 0; i < BATCH / THREADS; ++i) {
        int j = i * THREADS + t;
        if (j < bcount) {
            int d = dst[bstart + j];
            atomicAdd(&base[d >> shift], 1);
        }
    }
    __syncthreads();
    // exclusive scan over NB_MAX entries; thread t owns 2t, 2t+1
    int h0 = base[2 * t], h1 = base[2 * t + 1];
    int s = h0 + h1;
    int lane = t & 63, wid = t >> 6;
    int incl = s;
#pragma unroll
    for (int off = 1; off < 64; off <<= 1) {
        int v = __shfl_up(incl, off, 64);
        if (lane >= off) incl += v;
    }
    if (lane == 63) wsum[wid] = incl;
    __syncthreads();   // also guarantees all base[] reads (h0,h1) complete
    int woff = 0;
    for (int w = 0; w < wid; ++w) woff += wsum[w];
    int excl = woff + incl - s;
    // global reservation for this block's run in each owned bucket
    if (h0 > 0) gbase[2 * t] = atomicAdd(&bucket_cursor[2 * t], h0);
    if (h1 > 0) gbase[2 * t + 1] = atomicAdd(&bucket_cursor[2 * t + 1], h1);
    base[2 * t] = excl;
    base[2 * t + 1] = excl + h0;
    __syncthreads();
    // pass 2: scatter packed edges into LDS staging, bucket-ordered
#pragma unroll
    for (int i = 0; i < BATCH / THREADS; ++i) {
        int j = i * THREADS + t;
        if (j < bcount) {
            int d = dst[bstart + j];
            unsigned int s_ = (unsigned int)src[bstart + j];
            int b = d >> shift;
            int p = base[b] + atomicAdd(&cnt2[b], 1);
            st[p] = (s_ << shift) | ((unsigned int)d & lmask);
        }
    }
    __syncthreads();
    // flush: consecutive staging slots = contiguous global runs per bucket
    for (int j = t; j < bcount; j += THREADS) {
        int lo = 0, hi = NB_MAX - 1;           // rightmost b with base[b] <= j
        while (lo < hi) {
            int mid = (lo + hi + 1) >> 1;
            if (base[mid] <= j) lo = mid; else hi = mid - 1;
        }
        pairs[gbase[lo] + (j - base[lo])] = st[j];
    }
}

// ---------------------------------------------------------------------------
// k_bin2: final exact binning, bucket-local. 2 blocks per bucket; cursor
// window (~1KB) and CSR window (~32KB) stay L2-resident -> lines fully dirty.
// ---------------------------------------------------------------------------
#define SPLIT 2
__global__ void k_bin2(const unsigned int* __restrict__ pairs,
                       const int* __restrict__ bucket_base,
                       const int* __restrict__ bucket_cursor,  // == end after phase A
                       int* __restrict__ cursor, int* __restrict__ csr_src, int shift) {
    int b = blockIdx.x / SPLIT;
    int half = blockIdx.x % SPLIT;
    int start = bucket_base[b];
    int end = bucket_cursor[b];
    unsigned int lmask = (1u << shift) - 1u;
    int dbase = b << shift;
    for (int e = start + half * THREADS + threadIdx.x; e < end; e += SPLIT * THREADS) {
        unsigned int pr = pairs[e];
        int d = dbase | (int)(pr & lmask);
        int s = (int)(pr >> shift);
        int pos = atomicAdd(&cursor[d], 1);
        csr_src[pos] = s;
    }
}

// ---------------------------------------------------------------------------
// k_agg1: gather-side aggregation, 4 lanes per node (one float4 slice each).
// ---------------------------------------------------------------------------
__global__ void k_agg1(const int* __restrict__ row_start, const int* __restrict__ deg_in,
                       const int* __restrict__ csr_src, const float* __restrict__ feat,
                       float* __restrict__ agg, int nN) {
    int tid = blockIdx.x * blockDim.x + threadIdx.x;
    int n = tid >> 2, q = tid & 3;
    if (n >= nN) return;
    int row = row_start[n], deg = deg_in[n];
    const float* fb = feat + q * 4;
    float4 acc = make_float4(0.f, 0.f, 0.f, 0.f);
    int i = 0;
    for (; i + 4 <= deg; i += 4) {
        int s0 = csr_src[row + i];
        int s1 = csr_src[row + i + 1];
        int s2 = csr_src[row + i + 2];
        int s3 = csr_src[row + i + 3];
        float4 v0 = *(const float4*)(fb + (size_t)s0 * 16);
        float4 v1 = *(const float4*)(fb + (size_t)s1 * 16);
        float4 v2 = *(const float4*)(fb + (size_t)s2 * 16);
        float4 v3 = *(const float4*)(fb + (size_t)s3 * 16);
        acc.x += v0.x + v1.x + v2.x + v3.x;
        acc.y += v0.y + v1.y + v2.y + v3.y;
        acc.z += v0.z + v1.z + v2.z + v3.z;
        acc.w += v0.w + v1.w + v2.w + v3.w;
    }
    for (; i < deg; ++i) {
        int s0 = csr_src[row + i];
        float4 v0 = *(const float4*)(fb + (size_t)s0 * 16);
        acc.x += v0.x; acc.y += v0.y; acc.z += v0.z; acc.w += v0.w;
    }
    ((float4*)agg)[(size_t)n * 4 + q] = acc;
}

// ---------------------------------------------------------------------------
// k_mlp: chunked (live set ~48 floats, no scratch):
//   t = agg1*ri; per 16-wide chunk: yv = tanh(t@W1+b1); u += yv@W2; z = u*ro
// ---------------------------------------------------------------------------
__global__ __launch_bounds__(THREADS) void k_mlp(
    const float* __restrict__ agg1, const float* __restrict__ rsq_in,
    const float* __restrict__ rsq_out, const float* __restrict__ w1,
    const float* __restrict__ b1, const float* __restrict__ w2,
    float* __restrict__ z, int nN)
{
    int n = blockIdx.x * blockDim.x + threadIdx.x;
    if (n >= nN) return;
    float ri = rsq_in[n];
    const float4* a4 = (const float4*)(agg1 + (size_t)n * 16);
    float t[16];
#pragma unroll
    for (int k = 0; k < 4; ++k) {
        float4 v = a4[k];
        t[4*k+0] = v.x * ri; t[4*k+1] = v.y * ri;
        t[4*k+2] = v.z * ri; t[4*k+3] = v.w * ri;
    }
    float u[16];
#pragma unroll
    for (int o = 0; o < 16; ++o) u[o] = 0.f;
#pragma unroll
    for (int c = 0; c < 4; ++c) {
        float yv[16];
#pragma unroll
        for (int jj = 0; jj < 16; ++jj) yv[jj] = b1[c*16 + jj];
#pragma unroll
        for (int i = 0; i < 16; ++i) {
            float ti = t[i];
#pragma unroll
            for (int jj = 0; jj < 16; ++jj)
                yv[jj] = fmaf(ti, w1[i*64 + c*16 + jj], yv[jj]);
        }
#pragma unroll
        for (int jj = 0; jj < 16; ++jj) yv[jj] = tanhf(yv[jj]);
#pragma unroll
        for (int jj = 0; jj < 16; ++jj) {
            float yj = yv[jj];
#pragma unroll
            for (int o = 0; o < 16; ++o)
                u[o] = fmaf(yj, w2[(c*16 + jj)*16 + o], u[o]);
        }
    }
    float ro = rsq_out[n];
    float4* z4 = (float4*)(z + (size_t)n * 16);
#pragma unroll
    for (int k = 0; k < 4; ++k)
        z4[k] = make_float4(u[4*k+0]*ro, u[4*k+1]*ro, u[4*k+2]*ro, u[4*k+3]*ro);
}

// ---------------------------------------------------------------------------
// k_agg2: gather + fused epilogue (ri, b2, symplectic permute via shfl_xor 2).
// ---------------------------------------------------------------------------
__global__ void k_agg2(const int* __restrict__ row_start, const int* __restrict__ deg_in,
                       const int* __restrict__ csr_src, const float* __restrict__ feat,
                       const float* __restrict__ rsq_in, const float* __restrict__ b2,
                       float* __restrict__ out, int nN) {
    int tid = blockIdx.x * blockDim.x + threadIdx.x;
    int n = tid >> 2, q = tid & 3;
    if (n >= nN) return;
    int row = row_start[n], deg = deg_in[n];
    const float* fb = feat + q * 4;
    float4 acc = make_float4(0.f, 0.f, 0.f, 0.f);
    int i = 0;
    for (; i + 4 <= deg; i += 4) {
        int s0 = csr_src[row + i];
        int s1 = csr_src[row + i + 1];
        int s2 = csr_src[row + i + 2];
        int s3 = csr_src[row + i + 3];
        float4 v0 = *(const float4*)(fb + (size_t)s0 * 16);
        float4 v1 = *(const float4*)(fb + (size_t)s1 * 16);
        float4 v2 = *(const float4*)(fb + (size_t)s2 * 16);
        float4 v3 = *(const float4*)(fb + (size_t)s3 * 16);
        acc.x += v0.x + v1.x + v2.x + v3.x;
        acc.y += v0.y + v1.y + v2.y + v3.y;
        acc.z += v0.z + v1.z + v2.z + v3.z;
        acc.w += v0.w + v1.w + v2.w + v3.w;
    }
    for (; i < deg; ++i) {
        int s0 = csr_src[row + i];
        float4 v0 = *(const float4*)(fb + (size_t)s0 * 16);
        acc.x += v0.x; acc.y += v0.y; acc.z += v0.z; acc.w += v0.w;
    }
    float ri = rsq_in[n];
    float4 bq = *(const float4*)(b2 + q * 4);
    float4 g = make_float4(fmaf(acc.x, ri, bq.x), fmaf(acc.y, ri, bq.y),
                           fmaf(acc.z, ri, bq.z), fmaf(acc.w, ri, bq.w));
    float4 p;
    p.x = __shfl_xor(g.x, 2, 64);
    p.y = __shfl_xor(g.y, 2, 64);
    p.z = __shfl_xor(g.z, 2, 64);
    p.w = __shfl_xor(g.w, 2, 64);
    float sgn = (q < 2) ? 1.f : -1.f;
    ((float4*)out)[(size_t)n * 4 + q] =
        make_float4(sgn * p.x, sgn * p.y, sgn * p.z, sgn * p.w);
}

extern "C" void kernel_launch(void* const* d_in, const int* in_sizes, int n_in,
                              void* d_out, int out_size, void* d_ws, size_t ws_size,
                              hipStream_t stream) {
    const float* x  = (const float*)d_in[0];
    const int*   src = (const int*)d_in[1];
    const int*   dst = (const int*)d_in[2];
    const float* w1 = (const float*)d_in[3];
    const float* b1 = (const float*)d_in[4];
    const float* w2 = (const float*)d_in[5];
    const float* b2 = (const float*)d_in[6];
    float* out = (float*)d_out;

    const int nN = in_sizes[0] / 16;
    const int nE = in_sizes[1];

    // bucket shift: nodes-per-bucket = 1<<shift, NB <= NB_MAX
    int shift = 8;
    while ((((long long)nN + (1LL << shift) - 1) >> shift) > NB_MAX) shift++;
    const int NB = (int)(((long long)nN + (1LL << shift) - 1) >> shift);

    // Workspace carve-up (256B aligned). ~34 MB.
    char* ws = (char*)d_ws;
    size_t off = 0;
    auto carve = [&](size_t bytes) -> void* {
        void* p = ws + off;
        off += (bytes + 255) & ~(size_t)255;
        return p;
    };
    // [deg_out | deg_in | alloc(64) | bucket_cnt(NB_MAX)] -> single memset
    int* deg = (int*)carve(((size_t)2 * nN + 64 + NB_MAX) * sizeof(int));
    int* deg_out = deg;
    int* deg_in  = deg + nN;
    unsigned int* alloc = (unsigned int*)(deg + 2 * nN);
    int* bucket_cnt = deg + 2 * nN + 64;
    int* bucket_base   = (int*)carve((size_t)NB_MAX * sizeof(int));
    int* bucket_cursor = (int*)carve((size_t)NB_MAX * sizeof(int));
    float* rsq_out  = (float*)carve((size_t)nN * sizeof(float));
    float* rsq_in   = (float*)carve((size_t)nN * sizeof(float));
    int*   row_start = (int*)carve((size_t)nN * sizeof(int));
    int*   cursor    = (int*)carve((size_t)nN * sizeof(int));
    float* xs   = (float*)carve((size_t)nN * 16 * sizeof(float)); // xs, later z
    int*   csr_src = (int*)carve((size_t)nE * sizeof(int));
    // pairs (dead after k_bin2) aliases agg1 (live from k_agg1 on)
    void*  un = carve((size_t)nE * sizeof(unsigned int) > (size_t)nN * 16 * sizeof(float)
                      ? (size_t)nE * sizeof(unsigned int) : (size_t)nN * 16 * sizeof(float));
    unsigned int* pairs = (unsigned int*)un;
    float* agg1 = (float*)un;

    const int node_blocks = (nN + THREADS - 1) / THREADS;
    const int quad_blocks = (4 * nN + THREADS - 1) / THREADS;
    const int batch_blocks = (nE + BATCH - 1) / BATCH;

    // 1. zero degree tables + allocator + bucket counts
    hipMemsetAsync(deg, 0, ((size_t)2 * nN + 64 + NB_MAX) * sizeof(int), stream);
    // 2. degrees + bucket histogram
    k_degrees<<<1024, THREADS, 0, stream>>>(src, dst, deg_out, deg_in, bucket_cnt, shift, nE);
    // 3. bucket base/cursor scan (1 block)
    k_bscan<<<1, THREADS, 0, stream>>>(bucket_cnt, bucket_base, bucket_cursor);
    // 4. norms + xs + CSR row offsets
    k_prep<<<node_blocks, THREADS, 0, stream>>>(x, deg_out, deg_in, rsq_out, rsq_in,
                                                xs, row_start, cursor, alloc, nN);
    // 5. phase A: bucket-group edges with coalesced run writes
    k_bucketA<<<batch_blocks, THREADS, 0, stream>>>(src, dst, bucket_cursor, pairs, shift, nE);
    // 6. phase B: exact binning, bucket-local writes
    k_bin2<<<NB * SPLIT, THREADS, 0, stream>>>(pairs, bucket_base, bucket_cursor,
                                               cursor, csr_src, shift);
    // 7. layer-1 aggregation (gather-side, register accumulate)
    k_agg1<<<quad_blocks, THREADS, 0, stream>>>(row_start, deg_in, csr_src, xs, agg1, nN);
    // 8. fused MLP (W2 hoisted); writes z into xs
    k_mlp<<<node_blocks, THREADS, 0, stream>>>(agg1, rsq_in, rsq_out, w1, b1, w2, xs, nN);
    // 9. layer-2 aggregation + fused epilogue
    k_agg2<<<quad_blocks, THREADS, 0, stream>>>(row_start, deg_in, csr_src, xs,
                                                rsq_in, b2, out, nN);
}

// Round 10
// 367.169 us; speedup vs baseline: 15.2184x; 1.7579x over previous
//
#include <hip/hip_runtime.h>

#define THREADS 256
#define NB_MAX 512      // max bucket count
#define BATCH 4096      // edges per bucketing block
#define SHIFT 8         // 256 nodes per bucket (valid for nN <= 131072)

// ---------------------------------------------------------------------------
// k_hist: LDS-staged bucket histograms of src>>8 and dst>>8. No per-node
// atomics anywhere. 256 blocks grid-stride; flush ~2*512*256 global atomics.
// ---------------------------------------------------------------------------
__global__ void k_hist(const int* __restrict__ src, const int* __restrict__ dst,
                       int* __restrict__ cnt_src, int* __restrict__ cnt_dst, int nE) {
    __shared__ int hs[NB_MAX], hd[NB_MAX];
    for (int i = threadIdx.x; i < NB_MAX; i += THREADS) { hs[i] = 0; hd[i] = 0; }
    __syncthreads();
    int stride = gridDim.x * blockDim.x;
    for (int e = blockIdx.x * blockDim.x + threadIdx.x; e < nE; e += stride) {
        atomicAdd(&hs[src[e] >> SHIFT], 1);
        atomicAdd(&hd[dst[e] >> SHIFT], 1);
    }
    __syncthreads();
    for (int i = threadIdx.x; i < NB_MAX; i += THREADS) {
        int a = hs[i], b = hd[i];
        if (a) atomicAdd(&cnt_src[i], a);
        if (b) atomicAdd(&cnt_dst[i], b);
    }
}

// ---------------------------------------------------------------------------
// k_bscan: one block; exclusive scans of cnt_src and cnt_dst (512 entries
// each, thread t owns 2t,2t+1) -> base/cursor for both sides.
// ---------------------------------------------------------------------------
__global__ void k_bscan(const int* __restrict__ cnt_src, const int* __restrict__ cnt_dst,
                        int* __restrict__ base_src, int* __restrict__ cur_src,
                        int* __restrict__ base_dst, int* __restrict__ cur_dst) {
    __shared__ int wsA[4], wsB[4];
    int t = threadIdx.x, lane = t & 63, wid = t >> 6;
    int a0 = cnt_src[2*t], a1 = cnt_src[2*t+1];
    int b0 = cnt_dst[2*t], b1 = cnt_dst[2*t+1];
    int sa = a0 + a1, sb = b0 + b1;
    int ia = sa, ib = sb;
#pragma unroll
    for (int off = 1; off < 64; off <<= 1) {
        int va = __shfl_up(ia, off, 64);
        int vb = __shfl_up(ib, off, 64);
        if (lane >= off) { ia += va; ib += vb; }
    }
    if (lane == 63) { wsA[wid] = ia; wsB[wid] = ib; }
    __syncthreads();
    int wa = 0, wb = 0;
    for (int w = 0; w < wid; ++w) { wa += wsA[w]; wb += wsB[w]; }
    int ea = wa + ia - sa, eb = wb + ib - sb;
    base_src[2*t] = ea;      base_src[2*t+1] = ea + a0;
    cur_src[2*t]  = ea;      cur_src[2*t+1]  = ea + a0;
    base_dst[2*t] = eb;      base_dst[2*t+1] = eb + b0;
    cur_dst[2*t]  = eb;      cur_dst[2*t+1]  = eb + b0;
}

// ---------------------------------------------------------------------------
// k_bucket_dst: block counting-sort of a 4096-edge batch by dst-bucket; flush
// contiguous per-bucket runs to pairs[] at positions reserved with one
// atomicAdd per (block,bucket). Pack: (src<<8)|dst_local.
// ---------------------------------------------------------------------------
__global__ __launch_bounds__(THREADS) void k_bucket_dst(
    const int* __restrict__ src, const int* __restrict__ dst,
    int* __restrict__ cur_dst, unsigned int* __restrict__ pairs, int nE)
{
    __shared__ int base[NB_MAX];
    __shared__ int cnt2[NB_MAX];
    __shared__ int gbase[NB_MAX];
    __shared__ int wsum[4];
    __shared__ unsigned int st[BATCH];
    int t = threadIdx.x;
    int bstart = blockIdx.x * BATCH;
    int bcount = min(BATCH, nE - bstart);

    for (int i = t; i < NB_MAX; i += THREADS) { base[i] = 0; cnt2[i] = 0; }
    __syncthreads();
#pragma unroll
    for (int i = 0; i < BATCH / THREADS; ++i) {
        int j = i * THREADS + t;
        if (j < bcount) atomicAdd(&base[dst[bstart + j] >> SHIFT], 1);
    }
    __syncthreads();
    int h0 = base[2*t], h1 = base[2*t+1];
    int s = h0 + h1;
    int lane = t & 63, wid = t >> 6;
    int incl = s;
#pragma unroll
    for (int off = 1; off < 64; off <<= 1) {
        int v = __shfl_up(incl, off, 64);
        if (lane >= off) incl += v;
    }
    if (lane == 63) wsum[wid] = incl;
    __syncthreads();
    int woff = 0;
    for (int w = 0; w < wid; ++w) woff += wsum[w];
    int excl = woff + incl - s;
    if (h0 > 0) gbase[2*t]   = atomicAdd(&cur_dst[2*t], h0);
    if (h1 > 0) gbase[2*t+1] = atomicAdd(&cur_dst[2*t+1], h1);
    base[2*t] = excl;
    base[2*t+1] = excl + h0;
    __syncthreads();
#pragma unroll
    for (int i = 0; i < BATCH / THREADS; ++i) {
        int j = i * THREADS + t;
        if (j < bcount) {
            int d = dst[bstart + j];
            unsigned int s_ = (unsigned int)src[bstart + j];
            int b = d >> SHIFT;
            int p = base[b] + atomicAdd(&cnt2[b], 1);
            st[p] = (s_ << SHIFT) | ((unsigned int)d & 255u);
        }
    }
    __syncthreads();
    for (int j = t; j < bcount; j += THREADS) {
        int lo = 0, hi = NB_MAX - 1;
        while (lo < hi) {
            int mid = (lo + hi + 1) >> 1;
            if (base[mid] <= j) lo = mid; else hi = mid - 1;
        }
        pairs[gbase[lo] + (j - base[lo])] = st[j];
    }
}

// ---------------------------------------------------------------------------
// k_bucket_src: same structure keyed on src-bucket; payload is just the
// 1-byte local src id (all we need for per-node out-degree counting).
// ---------------------------------------------------------------------------
__global__ __launch_bounds__(THREADS) void k_bucket_src(
    const int* __restrict__ src, int* __restrict__ cur_src,
    unsigned char* __restrict__ psrc, int nE)
{
    __shared__ int base[NB_MAX];
    __shared__ int cnt2[NB_MAX];
    __shared__ int gbase[NB_MAX];
    __shared__ int wsum[4];
    __shared__ unsigned char st[BATCH];
    int t = threadIdx.x;
    int bstart = blockIdx.x * BATCH;
    int bcount = min(BATCH, nE - bstart);

    for (int i = t; i < NB_MAX; i += THREADS) { base[i] = 0; cnt2[i] = 0; }
    __syncthreads();
#pragma unroll
    for (int i = 0; i < BATCH / THREADS; ++i) {
        int j = i * THREADS + t;
        if (j < bcount) atomicAdd(&base[src[bstart + j] >> SHIFT], 1);
    }
    __syncthreads();
    int h0 = base[2*t], h1 = base[2*t+1];
    int s = h0 + h1;
    int lane = t & 63, wid = t >> 6;
    int incl = s;
#pragma unroll
    for (int off = 1; off < 64; off <<= 1) {
        int v = __shfl_up(incl, off, 64);
        if (lane >= off) incl += v;
    }
    if (lane == 63) wsum[wid] = incl;
    __syncthreads();
    int woff = 0;
    for (int w = 0; w < wid; ++w) woff += wsum[w];
    int excl = woff + incl - s;
    if (h0 > 0) gbase[2*t]   = atomicAdd(&cur_src[2*t], h0);
    if (h1 > 0) gbase[2*t+1] = atomicAdd(&cur_src[2*t+1], h1);
    base[2*t] = excl;
    base[2*t+1] = excl + h0;
    __syncthreads();
#pragma unroll
    for (int i = 0; i < BATCH / THREADS; ++i) {
        int j = i * THREADS + t;
        if (j < bcount) {
            int sv = src[bstart + j];
            int b = sv >> SHIFT;
            int p = base[b] + atomicAdd(&cnt2[b], 1);
            st[p] = (unsigned char)(sv & 255);
        }
    }
    __syncthreads();
    for (int j = t; j < bcount; j += THREADS) {
        int lo = 0, hi = NB_MAX - 1;
        while (lo < hi) {
            int mid = (lo + hi + 1) >> 1;
            if (base[mid] <= j) lo = mid; else hi = mid - 1;
        }
        psrc[gbase[lo] + (j - base[lo])] = st[j];
    }
}

// ---------------------------------------------------------------------------
// k_count_src: one block per src-bucket. LDS-count out-degrees (256 counters),
// then emit rsq_out and xs = x*ro with fully contiguous writes.
// ---------------------------------------------------------------------------
__global__ __launch_bounds__(THREADS) void k_count_src(
    const unsigned char* __restrict__ psrc, const int* __restrict__ base_src,
    const int* __restrict__ cnt_src, const float* __restrict__ x,
    float* __restrict__ rsq_out, float* __restrict__ xs, int nN)
{
    __shared__ int c[256];
    int t = threadIdx.x, b = blockIdx.x;
    c[t] = 0;
    __syncthreads();
    int start = base_src[b], end = start + cnt_src[b];
    for (int e = start + t; e < end; e += THREADS)
        atomicAdd(&c[psrc[e]], 1);
    __syncthreads();
    int n = (b << SHIFT) + t;
    if (n < nN) {
        int cc = c[t];
        float ro = rsqrtf((float)(cc > 1 ? cc : 1));
        rsq_out[n] = ro;
        const float4* x4 = (const float4*)(x + (size_t)n * 16);
        float4* xs4 = (float4*)(xs + (size_t)n * 16);
#pragma unroll
        for (int k = 0; k < 4; ++k) {
            float4 v = x4[k];
            v.x *= ro; v.y *= ro; v.z *= ro; v.w *= ro;
            xs4[k] = v;
        }
    }
}

// ---------------------------------------------------------------------------
// k_bin_dst: one block per dst-bucket. Pass 1: LDS-count deg_in. Block scan
// -> row_start = bucket_base + local exclusive (bucket-major == node order,
// so the global CSR scan falls out for free). Write deg_in/rsq_in/row_start
// contiguously. Pass 2: scatter src ids into csr_src via LDS cursors.
// ---------------------------------------------------------------------------
__global__ __launch_bounds__(THREADS) void k_bin_dst(
    const unsigned int* __restrict__ pairs, const int* __restrict__ base_dst,
    const int* __restrict__ cnt_dst, int* __restrict__ deg_in,
    float* __restrict__ rsq_in, int* __restrict__ row_start,
    int* __restrict__ csr_src, int nN)
{
    __shared__ int c[256];
    __shared__ int cur[256];
    __shared__ int wsum[4];
    int t = threadIdx.x, b = blockIdx.x;
    c[t] = 0;
    __syncthreads();
    int start = base_dst[b], end = start + cnt_dst[b];
    for (int e = start + t; e < end; e += THREADS)
        atomicAdd(&c[pairs[e] & 255u], 1);
    __syncthreads();
    int cc = c[t];
    int lane = t & 63, wid = t >> 6;
    int incl = cc;
#pragma unroll
    for (int off = 1; off < 64; off <<= 1) {
        int v = __shfl_up(incl, off, 64);
        if (lane >= off) incl += v;
    }
    if (lane == 63) wsum[wid] = incl;
    __syncthreads();
    int woff = 0;
    for (int w = 0; w < wid; ++w) woff += wsum[w];
    int rs = start + woff + incl - cc;
    cur[t] = rs;
    int n = (b << SHIFT) + t;
    if (n < nN) {
        deg_in[n] = cc;
        rsq_in[n] = rsqrtf((float)(cc > 1 ? cc : 1));
        row_start[n] = rs;
    }
    __syncthreads();
    for (int e = start + t; e < end; e += THREADS) {
        unsigned int pr = pairs[e];
        int pos = atomicAdd(&cur[pr & 255u], 1);
        csr_src[pos] = (int)(pr >> SHIFT);
    }
}

// ---------------------------------------------------------------------------
// k_agg1: gather-side aggregation, 4 lanes per node (one float4 slice each).
// ---------------------------------------------------------------------------
__global__ void k_agg1(const int* __restrict__ row_start, const int* __restrict__ deg_in,
                       const int* __restrict__ csr_src, const float* __restrict__ feat,
                       float* __restrict__ agg, int nN) {
    int tid = blockIdx.x * blockDim.x + threadIdx.x;
    int n = tid >> 2, q = tid & 3;
    if (n >= nN) return;
    int row = row_start[n], deg = deg_in[n];
    const float* fb = feat + q * 4;
    float4 acc = make_float4(0.f, 0.f, 0.f, 0.f);
    int i = 0;
    for (; i + 4 <= deg; i += 4) {
        int s0 = csr_src[row + i];
        int s1 = csr_src[row + i + 1];
        int s2 = csr_src[row + i + 2];
        int s3 = csr_src[row + i + 3];
        float4 v0 = *(const float4*)(fb + (size_t)s0 * 16);
        float4 v1 = *(const float4*)(fb + (size_t)s1 * 16);
        float4 v2 = *(const float4*)(fb + (size_t)s2 * 16);
        float4 v3 = *(const float4*)(fb + (size_t)s3 * 16);
        acc.x += v0.x + v1.x + v2.x + v3.x;
        acc.y += v0.y + v1.y + v2.y + v3.y;
        acc.z += v0.z + v1.z + v2.z + v3.z;
        acc.w += v0.w + v1.w + v2.w + v3.w;
    }
    for (; i < deg; ++i) {
        int s0 = csr_src[row + i];
        float4 v0 = *(const float4*)(fb + (size_t)s0 * 16);
        acc.x += v0.x; acc.y += v0.y; acc.z += v0.z; acc.w += v0.w;
    }
    ((float4*)agg)[(size_t)n * 4 + q] = acc;
}

// ---------------------------------------------------------------------------
// k_mlp: chunked; tanh via native v_exp_f32 + v_rcp_f32 (no libm path):
//   tanh(v) = 1 - 2 / (exp(2v) + 1)
// ---------------------------------------------------------------------------
__global__ __launch_bounds__(THREADS) void k_mlp(
    const float* __restrict__ agg1, const float* __restrict__ rsq_in,
    const float* __restrict__ rsq_out, const float* __restrict__ w1,
    const float* __restrict__ b1, const float* __restrict__ w2,
    float* __restrict__ z, int nN)
{
    int n = blockIdx.x * blockDim.x + threadIdx.x;
    if (n >= nN) return;
    float ri = rsq_in[n];
    const float4* a4 = (const float4*)(agg1 + (size_t)n * 16);
    float t[16];
#pragma unroll
    for (int k = 0; k < 4; ++k) {
        float4 v = a4[k];
        t[4*k+0] = v.x * ri; t[4*k+1] = v.y * ri;
        t[4*k+2] = v.z * ri; t[4*k+3] = v.w * ri;
    }
    float u[16];
#pragma unroll
    for (int o = 0; o < 16; ++o) u[o] = 0.f;
#pragma unroll
    for (int c = 0; c < 4; ++c) {
        float yv[16];
#pragma unroll
        for (int jj = 0; jj < 16; ++jj) yv[jj] = b1[c*16 + jj];
#pragma unroll
        for (int i = 0; i < 16; ++i) {
            float ti = t[i];
#pragma unroll
            for (int jj = 0; jj < 16; ++jj)
                yv[jj] = fmaf(ti, w1[i*64 + c*16 + jj], yv[jj]);
        }
#pragma unroll
        for (int jj = 0; jj < 16; ++jj) {
            float e = __expf(2.f * yv[jj]);
            yv[jj] = 1.f - 2.f * __builtin_amdgcn_rcpf(e + 1.f);
        }
#pragma unroll
        for (int jj = 0; jj < 16; ++jj) {
            float yj = yv[jj];
#pragma unroll
            for (int o = 0; o < 16; ++o)
                u[o] = fmaf(yj, w2[(c*16 + jj)*16 + o], u[o]);
        }
    }
    float ro = rsq_out[n];
    float4* z4 = (float4*)(z + (size_t)n * 16);
#pragma unroll
    for (int k = 0; k < 4; ++k)
        z4[k] = make_float4(u[4*k+0]*ro, u[4*k+1]*ro, u[4*k+2]*ro, u[4*k+3]*ro);
}

// ---------------------------------------------------------------------------
// k_agg2: gather + fused epilogue (ri, b2, symplectic permute via shfl_xor 2).
// ---------------------------------------------------------------------------
__global__ void k_agg2(const int* __restrict__ row_start, const int* __restrict__ deg_in,
                       const int* __restrict__ csr_src, const float* __restrict__ feat,
                       const float* __restrict__ rsq_in, const float* __restrict__ b2,
                       float* __restrict__ out, int nN) {
    int tid = blockIdx.x * blockDim.x + threadIdx.x;
    int n = tid >> 2, q = tid & 3;
    if (n >= nN) return;
    int row = row_start[n], deg = deg_in[n];
    const float* fb = feat + q * 4;
    float4 acc = make_float4(0.f, 0.f, 0.f, 0.f);
    int i = 0;
    for (; i + 4 <= deg; i += 4) {
        int s0 = csr_src[row + i];
        int s1 = csr_src[row + i + 1];
        int s2 = csr_src[row + i + 2];
        int s3 = csr_src[row + i + 3];
        float4 v0 = *(const float4*)(fb + (size_t)s0 * 16);
        float4 v1 = *(const float4*)(fb + (size_t)s1 * 16);
        float4 v2 = *(const float4*)(fb + (size_t)s2 * 16);
        float4 v3 = *(const float4*)(fb + (size_t)s3 * 16);
        acc.x += v0.x + v1.x + v2.x + v3.x;
        acc.y += v0.y + v1.y + v2.y + v3.y;
        acc.z += v0.z + v1.z + v2.z + v3.z;
        acc.w += v0.w + v1.w + v2.w + v3.w;
    }
    for (; i < deg; ++i) {
        int s0 = csr_src[row + i];
        float4 v0 = *(const float4*)(fb + (size_t)s0 * 16);
        acc.x += v0.x; acc.y += v0.y; acc.z += v0.z; acc.w += v0.w;
    }
    float ri = rsq_in[n];
    float4 bq = *(const float4*)(b2 + q * 4);
    float4 g = make_float4(fmaf(acc.x, ri, bq.x), fmaf(acc.y, ri, bq.y),
                           fmaf(acc.z, ri, bq.z), fmaf(acc.w, ri, bq.w));
    float4 p;
    p.x = __shfl_xor(g.x, 2, 64);
    p.y = __shfl_xor(g.y, 2, 64);
    p.z = __shfl_xor(g.z, 2, 64);
    p.w = __shfl_xor(g.w, 2, 64);
    float sgn = (q < 2) ? 1.f : -1.f;
    ((float4*)out)[(size_t)n * 4 + q] =
        make_float4(sgn * p.x, sgn * p.y, sgn * p.z, sgn * p.w);
}

extern "C" void kernel_launch(void* const* d_in, const int* in_sizes, int n_in,
                              void* d_out, int out_size, void* d_ws, size_t ws_size,
                              hipStream_t stream) {
    const float* x  = (const float*)d_in[0];
    const int*   src = (const int*)d_in[1];
    const int*   dst = (const int*)d_in[2];
    const float* w1 = (const float*)d_in[3];
    const float* b1 = (const float*)d_in[4];
    const float* w2 = (const float*)d_in[5];
    const float* b2 = (const float*)d_in[6];
    float* out = (float*)d_out;

    const int nN = in_sizes[0] / 16;
    const int nE = in_sizes[1];
    const int NB = (nN + (1 << SHIFT) - 1) >> SHIFT;   // 391 for nN=100k

    // Workspace carve-up (256B aligned). ~37 MB.
    char* ws = (char*)d_ws;
    size_t off = 0;
    auto carve = [&](size_t bytes) -> void* {
        void* p = ws + off;
        off += (bytes + 255) & ~(size_t)255;
        return p;
    };
    int* cnt_src = (int*)carve((size_t)2 * NB_MAX * sizeof(int));  // [cnt_src|cnt_dst]
    int* cnt_dst = cnt_src + NB_MAX;
    int* base_src = (int*)carve((size_t)NB_MAX * sizeof(int));
    int* cur_src  = (int*)carve((size_t)NB_MAX * sizeof(int));
    int* base_dst = (int*)carve((size_t)NB_MAX * sizeof(int));
    int* cur_dst  = (int*)carve((size_t)NB_MAX * sizeof(int));
    float* rsq_out  = (float*)carve((size_t)nN * sizeof(float));
    float* rsq_in   = (float*)carve((size_t)nN * sizeof(float));
    int*   row_start = (int*)carve((size_t)nN * sizeof(int));
    int*   deg_in    = (int*)carve((size_t)nN * sizeof(int));
    float* xs   = (float*)carve((size_t)nN * 16 * sizeof(float)); // xs, later z
    int*   csr_src = (int*)carve((size_t)nE * sizeof(int));
    unsigned char* psrc = (unsigned char*)carve((size_t)nE);
    // pairs (dead after k_bin_dst) aliases agg1 (live from k_agg1 on)
    size_t un_sz = (size_t)nE * 4 > (size_t)nN * 64 ? (size_t)nE * 4 : (size_t)nN * 64;
    void* un = carve(un_sz);
    unsigned int* pairs = (unsigned int*)un;
    float* agg1 = (float*)un;

    const int node_blocks = (nN + THREADS - 1) / THREADS;
    const int quad_blocks = (4 * nN + THREADS - 1) / THREADS;
    const int batch_blocks = (nE + BATCH - 1) / BATCH;

    // 1. zero bucket counts (4 KB)
    hipMemsetAsync(cnt_src, 0, (size_t)2 * NB_MAX * sizeof(int), stream);
    // 2. bucket histograms (src & dst) — no per-node atomics
    k_hist<<<256, THREADS, 0, stream>>>(src, dst, cnt_src, cnt_dst, nE);
    // 3. scan both
    k_bscan<<<1, THREADS, 0, stream>>>(cnt_src, cnt_dst, base_src, cur_src, base_dst, cur_dst);
    // 4. bucket-group edges by dst (packed src|dst_local)
    k_bucket_dst<<<batch_blocks, THREADS, 0, stream>>>(src, dst, cur_dst, pairs, nE);
    // 5. bucket-group src ids (1-byte locals)
    k_bucket_src<<<batch_blocks, THREADS, 0, stream>>>(src, cur_src, psrc, nE);
    // 6. out-degree counting + rsq_out + xs (all contiguous writes)
    k_count_src<<<NB, THREADS, 0, stream>>>(psrc, base_src, cnt_src, x, rsq_out, xs, nN);
    // 7. in-degree, rsq_in, row_start (free global scan), CSR scatter via LDS cursors
    k_bin_dst<<<NB, THREADS, 0, stream>>>(pairs, base_dst, cnt_dst, deg_in, rsq_in,
                                          row_start, csr_src, nN);
    // 8. layer-1 aggregation (gather-side, register accumulate)
    k_agg1<<<quad_blocks, THREADS, 0, stream>>>(row_start, deg_in, csr_src, xs, agg1, nN);
    // 9. fused MLP (W2 hoisted); writes z into xs
    k_mlp<<<node_blocks, THREADS, 0, stream>>>(agg1, rsq_in, rsq_out, w1, b1, w2, xs, nN);
    // 10. layer-2 aggregation + fused epilogue
    k_agg2<<<quad_blocks, THREADS, 0, stream>>>(row_start, deg_in, csr_src, xs,
                                                rsq_in, b2, out, nN);
}

// Round 11
// 317.943 us; speedup vs baseline: 17.5746x; 1.1548x over previous
//
#include <hip/hip_runtime.h>

#define THREADS 256
#define NB_MAX 512      // max bucket count
#define BATCH 4096      // edges per bucketing block
#define EPT (BATCH / THREADS)
#define SHIFT 8         // 256 nodes per bucket (valid for nN <= 131072)

// ---------------------------------------------------------------------------
// k_hist: LDS-staged bucket histograms of src>>8 and dst>>8, int4 loads.
// ---------------------------------------------------------------------------
__global__ void k_hist(const int* __restrict__ src, const int* __restrict__ dst,
                       int* __restrict__ cnt_src, int* __restrict__ cnt_dst, int nE) {
    __shared__ int hs[NB_MAX], hd[NB_MAX];
    for (int i = threadIdx.x; i < NB_MAX; i += THREADS) { hs[i] = 0; hd[i] = 0; }
    __syncthreads();
    int gid = blockIdx.x * blockDim.x + threadIdx.x;
    int stride = gridDim.x * blockDim.x;
    int nE4 = nE >> 2;
    for (int e4 = gid; e4 < nE4; e4 += stride) {
        int4 s4 = ((const int4*)src)[e4];
        int4 d4 = ((const int4*)dst)[e4];
        atomicAdd(&hs[s4.x >> SHIFT], 1);
        atomicAdd(&hs[s4.y >> SHIFT], 1);
        atomicAdd(&hs[s4.z >> SHIFT], 1);
        atomicAdd(&hs[s4.w >> SHIFT], 1);
        atomicAdd(&hd[d4.x >> SHIFT], 1);
        atomicAdd(&hd[d4.y >> SHIFT], 1);
        atomicAdd(&hd[d4.z >> SHIFT], 1);
        atomicAdd(&hd[d4.w >> SHIFT], 1);
    }
    for (int e = (nE4 << 2) + gid; e < nE; e += stride) {
        atomicAdd(&hs[src[e] >> SHIFT], 1);
        atomicAdd(&hd[dst[e] >> SHIFT], 1);
    }
    __syncthreads();
    for (int i = threadIdx.x; i < NB_MAX; i += THREADS) {
        int a = hs[i], b = hd[i];
        if (a) atomicAdd(&cnt_src[i], a);
        if (b) atomicAdd(&cnt_dst[i], b);
    }
}

// ---------------------------------------------------------------------------
// k_bscan: one block; exclusive scans of cnt_src and cnt_dst (512 entries
// each, thread t owns 2t,2t+1) -> base/cursor for both sides.
// ---------------------------------------------------------------------------
__global__ void k_bscan(const int* __restrict__ cnt_src, const int* __restrict__ cnt_dst,
                        int* __restrict__ base_src, int* __restrict__ cur_src,
                        int* __restrict__ base_dst, int* __restrict__ cur_dst) {
    __shared__ int wsA[4], wsB[4];
    int t = threadIdx.x, lane = t & 63, wid = t >> 6;
    int a0 = cnt_src[2*t], a1 = cnt_src[2*t+1];
    int b0 = cnt_dst[2*t], b1 = cnt_dst[2*t+1];
    int sa = a0 + a1, sb = b0 + b1;
    int ia = sa, ib = sb;
#pragma unroll
    for (int off = 1; off < 64; off <<= 1) {
        int va = __shfl_up(ia, off, 64);
        int vb = __shfl_up(ib, off, 64);
        if (lane >= off) { ia += va; ib += vb; }
    }
    if (lane == 63) { wsA[wid] = ia; wsB[wid] = ib; }
    __syncthreads();
    int wa = 0, wb = 0;
    for (int w = 0; w < wid; ++w) { wa += wsA[w]; wb += wsB[w]; }
    int ea = wa + ia - sa, eb = wb + ib - sb;
    base_src[2*t] = ea;      base_src[2*t+1] = ea + a0;
    cur_src[2*t]  = ea;      cur_src[2*t+1]  = ea + a0;
    base_dst[2*t] = eb;      base_dst[2*t+1] = eb + b0;
    cur_dst[2*t]  = eb;      cur_dst[2*t+1]  = eb + b0;
}

// ---------------------------------------------------------------------------
// k_bucket_both: fused dst- and src-side bucketing. One read of src/dst
// (kept in registers across phases), dual LDS histogram + dual scan, dual
// LDS scatter staged WITH the bucket id (ushort) so the flush needs NO
// binary search — just st_b[j] -> gbase/base lookup -> coalesced run write.
//   dst side: pairs[] gets (src<<8)|dst_local
//   src side: psrc[]  gets 1-byte local src id
// ---------------------------------------------------------------------------
__global__ __launch_bounds__(THREADS) void k_bucket_both(
    const int* __restrict__ src, const int* __restrict__ dst,
    int* __restrict__ cur_dst, int* __restrict__ cur_src,
    unsigned int* __restrict__ pairs, unsigned char* __restrict__ psrc, int nE)
{
    __shared__ int base_d[NB_MAX], gbase_d[NB_MAX], cnt2_d[NB_MAX];
    __shared__ int base_s[NB_MAX], gbase_s[NB_MAX], cnt2_s[NB_MAX];
    __shared__ int wsA[4], wsB[4];
    __shared__ unsigned int   st_p[BATCH];   // packed pair payload
    __shared__ unsigned short st_bd[BATCH];  // bucket id of staged slot (dst side)
    __shared__ unsigned char  st_s[BATCH];   // local src id payload
    __shared__ unsigned short st_bs[BATCH];  // bucket id of staged slot (src side)

    int t = threadIdx.x;
    int bstart = blockIdx.x * BATCH;
    int bcount = min(BATCH, nE - bstart);

    for (int i = t; i < NB_MAX; i += THREADS) {
        base_d[i] = 0; cnt2_d[i] = 0;
        base_s[i] = 0; cnt2_s[i] = 0;
    }
    __syncthreads();

    // phase 1: load edges to registers + dual histogram
    int sv[EPT], dv[EPT];
#pragma unroll
    for (int i = 0; i < EPT; ++i) {
        int j = i * THREADS + t;
        if (j < bcount) {
            sv[i] = src[bstart + j];
            dv[i] = dst[bstart + j];
            atomicAdd(&base_d[dv[i] >> SHIFT], 1);
            atomicAdd(&base_s[sv[i] >> SHIFT], 1);
        }
    }
    __syncthreads();

    // phase 2: dual exclusive scan (thread t owns entries 2t, 2t+1)
    int hd0 = base_d[2*t], hd1 = base_d[2*t+1];
    int hs0 = base_s[2*t], hs1 = base_s[2*t+1];
    int sd = hd0 + hd1, ss = hs0 + hs1;
    int lane = t & 63, wid = t >> 6;
    int id_ = sd, is_ = ss;
#pragma unroll
    for (int off = 1; off < 64; off <<= 1) {
        int vd = __shfl_up(id_, off, 64);
        int vs = __shfl_up(is_, off, 64);
        if (lane >= off) { id_ += vd; is_ += vs; }
    }
    if (lane == 63) { wsA[wid] = id_; wsB[wid] = is_; }
    __syncthreads();
    int wd = 0, ws_ = 0;
    for (int w = 0; w < wid; ++w) { wd += wsA[w]; ws_ += wsB[w]; }
    int excl_d = wd + id_ - sd;
    int excl_s = ws_ + is_ - ss;
    // global run reservations (one atomic per non-empty (block,bucket))
    if (hd0 > 0) gbase_d[2*t]   = atomicAdd(&cur_dst[2*t],   hd0);
    if (hd1 > 0) gbase_d[2*t+1] = atomicAdd(&cur_dst[2*t+1], hd1);
    if (hs0 > 0) gbase_s[2*t]   = atomicAdd(&cur_src[2*t],   hs0);
    if (hs1 > 0) gbase_s[2*t+1] = atomicAdd(&cur_src[2*t+1], hs1);
    base_d[2*t] = excl_d;  base_d[2*t+1] = excl_d + hd0;
    base_s[2*t] = excl_s;  base_s[2*t+1] = excl_s + hs0;
    __syncthreads();

    // phase 3: dual scatter into LDS staging, recording bucket ids
#pragma unroll
    for (int i = 0; i < EPT; ++i) {
        int j = i * THREADS + t;
        if (j < bcount) {
            int d = dv[i], s = sv[i];
            int bd = d >> SHIFT, bs = s >> SHIFT;
            int pd = base_d[bd] + atomicAdd(&cnt2_d[bd], 1);
            st_p[pd]  = ((unsigned int)s << SHIFT) | ((unsigned int)d & 255u);
            st_bd[pd] = (unsigned short)bd;
            int ps = base_s[bs] + atomicAdd(&cnt2_s[bs], 1);
            st_s[ps]  = (unsigned char)(s & 255);
            st_bs[ps] = (unsigned short)bs;
        }
    }
    __syncthreads();

    // phase 4: flush — no binary search; contiguous run writes per bucket
    for (int j = t; j < bcount; j += THREADS) {
        int bd = st_bd[j];
        pairs[gbase_d[bd] + (j - base_d[bd])] = st_p[j];
        int bs = st_bs[j];
        psrc[gbase_s[bs] + (j - base_s[bs])] = st_s[j];
    }
}

// ---------------------------------------------------------------------------
// k_count_src: one block per src-bucket. LDS-count out-degrees (256 counters),
// then emit rsq_out and xs = x*ro with fully contiguous writes.
// ---------------------------------------------------------------------------
__global__ __launch_bounds__(THREADS) void k_count_src(
    const unsigned char* __restrict__ psrc, const int* __restrict__ base_src,
    const int* __restrict__ cnt_src, const float* __restrict__ x,
    float* __restrict__ rsq_out, float* __restrict__ xs, int nN)
{
    __shared__ int c[256];
    int t = threadIdx.x, b = blockIdx.x;
    c[t] = 0;
    __syncthreads();
    int start = base_src[b], end = start + cnt_src[b];
    for (int e = start + t; e < end; e += THREADS)
        atomicAdd(&c[psrc[e]], 1);
    __syncthreads();
    int n = (b << SHIFT) + t;
    if (n < nN) {
        int cc = c[t];
        float ro = rsqrtf((float)(cc > 1 ? cc : 1));
        rsq_out[n] = ro;
        const float4* x4 = (const float4*)(x + (size_t)n * 16);
        float4* xs4 = (float4*)(xs + (size_t)n * 16);
#pragma unroll
        for (int k = 0; k < 4; ++k) {
            float4 v = x4[k];
            v.x *= ro; v.y *= ro; v.z *= ro; v.w *= ro;
            xs4[k] = v;
        }
    }
}

// ---------------------------------------------------------------------------
// k_bin_dst: one block per dst-bucket. Pass 1: LDS-count deg_in. Block scan
// -> row_start = bucket_base + local exclusive (bucket-major == node order).
// Write deg_in/rsq_in/row_start contiguously. Pass 2: scatter src ids into
// csr_src via LDS cursors (bucket-local 32KB window stays L2-resident).
// ---------------------------------------------------------------------------
__global__ __launch_bounds__(THREADS) void k_bin_dst(
    const unsigned int* __restrict__ pairs, const int* __restrict__ base_dst,
    const int* __restrict__ cnt_dst, int* __restrict__ deg_in,
    float* __restrict__ rsq_in, int* __restrict__ row_start,
    int* __restrict__ csr_src, int nN)
{
    __shared__ int c[256];
    __shared__ int cur[256];
    __shared__ int wsum[4];
    int t = threadIdx.x, b = blockIdx.x;
    c[t] = 0;
    __syncthreads();
    int start = base_dst[b], end = start + cnt_dst[b];
    for (int e = start + t; e < end; e += THREADS)
        atomicAdd(&c[pairs[e] & 255u], 1);
    __syncthreads();
    int cc = c[t];
    int lane = t & 63, wid = t >> 6;
    int incl = cc;
#pragma unroll
    for (int off = 1; off < 64; off <<= 1) {
        int v = __shfl_up(incl, off, 64);
        if (lane >= off) incl += v;
    }
    if (lane == 63) wsum[wid] = incl;
    __syncthreads();
    int woff = 0;
    for (int w = 0; w < wid; ++w) woff += wsum[w];
    int rs = start + woff + incl - cc;
    cur[t] = rs;
    int n = (b << SHIFT) + t;
    if (n < nN) {
        deg_in[n] = cc;
        rsq_in[n] = rsqrtf((float)(cc > 1 ? cc : 1));
        row_start[n] = rs;
    }
    __syncthreads();
    for (int e = start + t; e < end; e += THREADS) {
        unsigned int pr = pairs[e];
        int pos = atomicAdd(&cur[pr & 255u], 1);
        csr_src[pos] = (int)(pr >> SHIFT);
    }
}

// ---------------------------------------------------------------------------
// k_agg1: gather-side aggregation, 4 lanes per node (one float4 slice each).
// ---------------------------------------------------------------------------
__global__ void k_agg1(const int* __restrict__ row_start, const int* __restrict__ deg_in,
                       const int* __restrict__ csr_src, const float* __restrict__ feat,
                       float* __restrict__ agg, int nN) {
    int tid = blockIdx.x * blockDim.x + threadIdx.x;
    int n = tid >> 2, q = tid & 3;
    if (n >= nN) return;
    int row = row_start[n], deg = deg_in[n];
    const float* fb = feat + q * 4;
    float4 acc = make_float4(0.f, 0.f, 0.f, 0.f);
    int i = 0;
    for (; i + 4 <= deg; i += 4) {
        int s0 = csr_src[row + i];
        int s1 = csr_src[row + i + 1];
        int s2 = csr_src[row + i + 2];
        int s3 = csr_src[row + i + 3];
        float4 v0 = *(const float4*)(fb + (size_t)s0 * 16);
        float4 v1 = *(const float4*)(fb + (size_t)s1 * 16);
        float4 v2 = *(const float4*)(fb + (size_t)s2 * 16);
        float4 v3 = *(const float4*)(fb + (size_t)s3 * 16);
        acc.x += v0.x + v1.x + v2.x + v3.x;
        acc.y += v0.y + v1.y + v2.y + v3.y;
        acc.z += v0.z + v1.z + v2.z + v3.z;
        acc.w += v0.w + v1.w + v2.w + v3.w;
    }
    for (; i < deg; ++i) {
        int s0 = csr_src[row + i];
        float4 v0 = *(const float4*)(fb + (size_t)s0 * 16);
        acc.x += v0.x; acc.y += v0.y; acc.z += v0.z; acc.w += v0.w;
    }
    ((float4*)agg)[(size_t)n * 4 + q] = acc;
}

// ---------------------------------------------------------------------------
// k_mlp: chunked; tanh via native v_exp_f32 + v_rcp_f32 (no libm path):
//   tanh(v) = 1 - 2 / (exp(2v) + 1)
// ---------------------------------------------------------------------------
__global__ __launch_bounds__(THREADS) void k_mlp(
    const float* __restrict__ agg1, const float* __restrict__ rsq_in,
    const float* __restrict__ rsq_out, const float* __restrict__ w1,
    const float* __restrict__ b1, const float* __restrict__ w2,
    float* __restrict__ z, int nN)
{
    int n = blockIdx.x * blockDim.x + threadIdx.x;
    if (n >= nN) return;
    float ri = rsq_in[n];
    const float4* a4 = (const float4*)(agg1 + (size_t)n * 16);
    float t[16];
#pragma unroll
    for (int k = 0; k < 4; ++k) {
        float4 v = a4[k];
        t[4*k+0] = v.x * ri; t[4*k+1] = v.y * ri;
        t[4*k+2] = v.z * ri; t[4*k+3] = v.w * ri;
    }
    float u[16];
#pragma unroll
    for (int o = 0; o < 16; ++o) u[o] = 0.f;
#pragma unroll
    for (int c = 0; c < 4; ++c) {
        float yv[16];
#pragma unroll
        for (int jj = 0; jj < 16; ++jj) yv[jj] = b1[c*16 + jj];
#pragma unroll
        for (int i = 0; i < 16; ++i) {
            float ti = t[i];
#pragma unroll
            for (int jj = 0; jj < 16; ++jj)
                yv[jj] = fmaf(ti, w1[i*64 + c*16 + jj], yv[jj]);
        }
#pragma unroll
        for (int jj = 0; jj < 16; ++jj) {
            float e = __expf(2.f * yv[jj]);
            yv[jj] = 1.f - 2.f * __builtin_amdgcn_rcpf(e + 1.f);
        }
#pragma unroll
        for (int jj = 0; jj < 16; ++jj) {
            float yj = yv[jj];
#pragma unroll
            for (int o = 0; o < 16; ++o)
                u[o] = fmaf(yj, w2[(c*16 + jj)*16 + o], u[o]);
        }
    }
    float ro = rsq_out[n];
    float4* z4 = (float4*)(z + (size_t)n * 16);
#pragma unroll
    for (int k = 0; k < 4; ++k)
        z4[k] = make_float4(u[4*k+0]*ro, u[4*k+1]*ro, u[4*k+2]*ro, u[4*k+3]*ro);
}

// ---------------------------------------------------------------------------
// k_agg2: gather + fused epilogue (ri, b2, symplectic permute via shfl_xor 2).
// ---------------------------------------------------------------------------
__global__ void k_agg2(const int* __restrict__ row_start, const int* __restrict__ deg_in,
                       const int* __restrict__ csr_src, const float* __restrict__ feat,
                       const float* __restrict__ rsq_in, const float* __restrict__ b2,
                       float* __restrict__ out, int nN) {
    int tid = blockIdx.x * blockDim.x + threadIdx.x;
    int n = tid >> 2, q = tid & 3;
    if (n >= nN) return;
    int row = row_start[n], deg = deg_in[n];
    const float* fb = feat + q * 4;
    float4 acc = make_float4(0.f, 0.f, 0.f, 0.f);
    int i = 0;
    for (; i + 4 <= deg; i += 4) {
        int s0 = csr_src[row + i];
        int s1 = csr_src[row + i + 1];
        int s2 = csr_src[row + i + 2];
        int s3 = csr_src[row + i + 3];
        float4 v0 = *(const float4*)(fb + (size_t)s0 * 16);
        float4 v1 = *(const float4*)(fb + (size_t)s1 * 16);
        float4 v2 = *(const float4*)(fb + (size_t)s2 * 16);
        float4 v3 = *(const float4*)(fb + (size_t)s3 * 16);
        acc.x += v0.x + v1.x + v2.x + v3.x;
        acc.y += v0.y + v1.y + v2.y + v3.y;
        acc.z += v0.z + v1.z + v2.z + v3.z;
        acc.w += v0.w + v1.w + v2.w + v3.w;
    }
    for (; i < deg; ++i) {
        int s0 = csr_src[row + i];
        float4 v0 = *(const float4*)(fb + (size_t)s0 * 16);
        acc.x += v0.x; acc.y += v0.y; acc.z += v0.z; acc.w += v0.w;
    }
    float ri = rsq_in[n];
    float4 bq = *(const float4*)(b2 + q * 4);
    float4 g = make_float4(fmaf(acc.x, ri, bq.x), fmaf(acc.y, ri, bq.y),
                           fmaf(acc.z, ri, bq.z), fmaf(acc.w, ri, bq.w));
    float4 p;
    p.x = __shfl_xor(g.x, 2, 64);
    p.y = __shfl_xor(g.y, 2, 64);
    p.z = __shfl_xor(g.z, 2, 64);
    p.w = __shfl_xor(g.w, 2, 64);
    float sgn = (q < 2) ? 1.f : -1.f;
    ((float4*)out)[(size_t)n * 4 + q] =
        make_float4(sgn * p.x, sgn * p.y, sgn * p.z, sgn * p.w);
}

extern "C" void kernel_launch(void* const* d_in, const int* in_sizes, int n_in,
                              void* d_out, int out_size, void* d_ws, size_t ws_size,
                              hipStream_t stream) {
    const float* x  = (const float*)d_in[0];
    const int*   src = (const int*)d_in[1];
    const int*   dst = (const int*)d_in[2];
    const float* w1 = (const float*)d_in[3];
    const float* b1 = (const float*)d_in[4];
    const float* w2 = (const float*)d_in[5];
    const float* b2 = (const float*)d_in[6];
    float* out = (float*)d_out;

    const int nN = in_sizes[0] / 16;
    const int nE = in_sizes[1];
    const int NB = (nN + (1 << SHIFT) - 1) >> SHIFT;   // 391 for nN=100k

    // Workspace carve-up (256B aligned). ~37 MB.
    char* ws = (char*)d_ws;
    size_t off = 0;
    auto carve = [&](size_t bytes) -> void* {
        void* p = ws + off;
        off += (bytes + 255) & ~(size_t)255;
        return p;
    };
    int* cnt_src = (int*)carve((size_t)2 * NB_MAX * sizeof(int));  // [cnt_src|cnt_dst]
    int* cnt_dst = cnt_src + NB_MAX;
    int* base_src = (int*)carve((size_t)NB_MAX * sizeof(int));
    int* cur_src  = (int*)carve((size_t)NB_MAX * sizeof(int));
    int* base_dst = (int*)carve((size_t)NB_MAX * sizeof(int));
    int* cur_dst  = (int*)carve((size_t)NB_MAX * sizeof(int));
    float* rsq_out  = (float*)carve((size_t)nN * sizeof(float));
    float* rsq_in   = (float*)carve((size_t)nN * sizeof(float));
    int*   row_start = (int*)carve((size_t)nN * sizeof(int));
    int*   deg_in    = (int*)carve((size_t)nN * sizeof(int));
    float* xs   = (float*)carve((size_t)nN * 16 * sizeof(float)); // xs, later z
    int*   csr_src = (int*)carve((size_t)nE * sizeof(int));
    unsigned char* psrc = (unsigned char*)carve((size_t)nE);
    // pairs (dead after k_bin_dst) aliases agg1 (live from k_agg1 on)
    size_t un_sz = (size_t)nE * 4 > (size_t)nN * 64 ? (size_t)nE * 4 : (size_t)nN * 64;
    void* un = carve(un_sz);
    unsigned int* pairs = (unsigned int*)un;
    float* agg1 = (float*)un;

    const int node_blocks = (nN + THREADS - 1) / THREADS;
    const int quad_blocks = (4 * nN + THREADS - 1) / THREADS;
    const int batch_blocks = (nE + BATCH - 1) / BATCH;

    // 1. zero bucket counts (4 KB)
    hipMemsetAsync(cnt_src, 0, (size_t)2 * NB_MAX * sizeof(int), stream);
    // 2. bucket histograms (src & dst) — no per-node atomics
    k_hist<<<256, THREADS, 0, stream>>>(src, dst, cnt_src, cnt_dst, nE);
    // 3. scan both
    k_bscan<<<1, THREADS, 0, stream>>>(cnt_src, cnt_dst, base_src, cur_src, base_dst, cur_dst);
    // 4. fused bucket-grouping of edges by dst AND src (one edge read pass,
    //    no binary search in flush)
    k_bucket_both<<<batch_blocks, THREADS, 0, stream>>>(src, dst, cur_dst, cur_src,
                                                        pairs, psrc, nE);
    // 5. out-degree counting + rsq_out + xs (all contiguous writes)
    k_count_src<<<NB, THREADS, 0, stream>>>(psrc, base_src, cnt_src, x, rsq_out, xs, nN);
    // 6. in-degree, rsq_in, row_start (free global scan), CSR scatter via LDS cursors
    k_bin_dst<<<NB, THREADS, 0, stream>>>(pairs, base_dst, cnt_dst, deg_in, rsq_in,
                                          row_start, csr_src, nN);
    // 7. layer-1 aggregation (gather-side, register accumulate)
    k_agg1<<<quad_blocks, THREADS, 0, stream>>>(row_start, deg_in, csr_src, xs, agg1, nN);
    // 8. fused MLP (W2 hoisted); writes z into xs
    k_mlp<<<node_blocks, THREADS, 0, stream>>>(agg1, rsq_in, rsq_out, w1, b1, w2, xs, nN);
    // 9. layer-2 aggregation + fused epilogue
    k_agg2<<<quad_blocks, THREADS, 0, stream>>>(row_start, deg_in, csr_src, xs,
                                                rsq_in, b2, out, nN);
}

// Round 15
// 309.190 us; speedup vs baseline: 18.0721x; 1.0283x over previous
//
#include <hip/hip_runtime.h>

#define THREADS 256
#define NB_MAX 512      // max bucket count (scan width)
#define BATCH 4096      // edges per bucketing block
#define EPT (BATCH / THREADS)
#define EPT4 (EPT / 4)
#define SHIFT 8         // 256 nodes per bucket (valid for nN <= 131072)

// ---------------------------------------------------------------------------
// k_hist: LDS-staged bucket histograms of src>>8 and dst>>8, int4 loads.
// ---------------------------------------------------------------------------
__global__ void k_hist(const int* __restrict__ src, const int* __restrict__ dst,
                       int* __restrict__ cnt_src, int* __restrict__ cnt_dst, int nE) {
    __shared__ int hs[NB_MAX], hd[NB_MAX];
    for (int i = threadIdx.x; i < NB_MAX; i += THREADS) { hs[i] = 0; hd[i] = 0; }
    __syncthreads();
    int gid = blockIdx.x * blockDim.x + threadIdx.x;
    int stride = gridDim.x * blockDim.x;
    int nE4 = nE >> 2;
    for (int e4 = gid; e4 < nE4; e4 += stride) {
        int4 s4 = ((const int4*)src)[e4];
        int4 d4 = ((const int4*)dst)[e4];
        atomicAdd(&hs[s4.x >> SHIFT], 1);
        atomicAdd(&hs[s4.y >> SHIFT], 1);
        atomicAdd(&hs[s4.z >> SHIFT], 1);
        atomicAdd(&hs[s4.w >> SHIFT], 1);
        atomicAdd(&hd[d4.x >> SHIFT], 1);
        atomicAdd(&hd[d4.y >> SHIFT], 1);
        atomicAdd(&hd[d4.z >> SHIFT], 1);
        atomicAdd(&hd[d4.w >> SHIFT], 1);
    }
    for (int e = (nE4 << 2) + gid; e < nE; e += stride) {
        atomicAdd(&hs[src[e] >> SHIFT], 1);
        atomicAdd(&hd[dst[e] >> SHIFT], 1);
    }
    __syncthreads();
    for (int i = threadIdx.x; i < NB_MAX; i += THREADS) {
        int a = hs[i], b = hd[i];
        if (a) atomicAdd(&cnt_src[i], a);
        if (b) atomicAdd(&cnt_dst[i], b);
    }
}

// ---------------------------------------------------------------------------
// k_bscan: one block; exclusive scans of cnt_src and cnt_dst (512 entries
// each, thread t owns 2t,2t+1) -> base/cursor for both sides.
// ---------------------------------------------------------------------------
__global__ void k_bscan(const int* __restrict__ cnt_src, const int* __restrict__ cnt_dst,
                        int* __restrict__ base_src, int* __restrict__ cur_src,
                        int* __restrict__ base_dst, int* __restrict__ cur_dst) {
    __shared__ int wsA[4], wsB[4];
    int t = threadIdx.x, lane = t & 63, wid = t >> 6;
    int a0 = cnt_src[2*t], a1 = cnt_src[2*t+1];
    int b0 = cnt_dst[2*t], b1 = cnt_dst[2*t+1];
    int sa = a0 + a1, sb = b0 + b1;
    int ia = sa, ib = sb;
#pragma unroll
    for (int off = 1; off < 64; off <<= 1) {
        int va = __shfl_up(ia, off, 64);
        int vb = __shfl_up(ib, off, 64);
        if (lane >= off) { ia += va; ib += vb; }
    }
    if (lane == 63) { wsA[wid] = ia; wsB[wid] = ib; }
    __syncthreads();
    int wa = 0, wb = 0;
    for (int w = 0; w < wid; ++w) { wa += wsA[w]; wb += wsB[w]; }
    int ea = wa + ia - sa, eb = wb + ib - sb;
    base_src[2*t] = ea;      base_src[2*t+1] = ea + a0;
    cur_src[2*t]  = ea;      cur_src[2*t+1]  = ea + a0;
    base_dst[2*t] = eb;      base_dst[2*t+1] = eb + b0;
    cur_dst[2*t]  = eb;      cur_dst[2*t+1]  = eb + b0;
}

// ---------------------------------------------------------------------------
// k_bucket_both: fused dst- and src-side bucketing. LDS diet vs prior round:
//  - base arrays double as scatter cursors (counting-sort invariant:
//    after scatter base[b] == orig_base[b+1], so flush recovers
//    orig_base[b] = b ? base[b-1] : 0)            [-8 KB cnt2]
//  - per-slot bucket ids replaced by a 512B coarse table jb[k] = bucket of
//    slot 16k + short monotone advance             [-16 KB st_bd/st_bs]
//  => ~29 KB LDS, 5 blocks/CU (was 49.6 KB / 3).
// ---------------------------------------------------------------------------
__global__ __launch_bounds__(THREADS) void k_bucket_both(
    const int* __restrict__ src, const int* __restrict__ dst,
    int* __restrict__ cur_dst, int* __restrict__ cur_src,
    unsigned int* __restrict__ pairs, unsigned char* __restrict__ psrc, int nE)
{
    __shared__ int base_d[NB_MAX], gbase_d[NB_MAX];
    __shared__ int base_s[NB_MAX], gbase_s[NB_MAX];
    __shared__ int wsA[4], wsB[4];
    __shared__ unsigned int  st_p[BATCH];                 // packed pair payload
    __shared__ unsigned char st_s[BATCH];                 // local src id payload
    __shared__ unsigned short jb_d[BATCH / 16], jb_s[BATCH / 16];

    int t = threadIdx.x;
    int bstart = blockIdx.x * BATCH;
    int bcount = min(BATCH, nE - bstart);
    int n4 = bcount >> 2;
    int tail = bcount - (n4 << 2);

    for (int i = t; i < NB_MAX; i += THREADS) { base_d[i] = 0; base_s[i] = 0; }
    __syncthreads();

    // phase 1: int4 edge loads to registers + dual LDS histogram
    int4 sv4[EPT4], dv4[EPT4];
    int sv_t = 0, dv_t = 0;
    bool have_t = (t < tail);
#pragma unroll
    for (int i = 0; i < EPT4; ++i) {
        int q = i * THREADS + t;
        if (q < n4) {
            sv4[i] = ((const int4*)(src + bstart))[q];
            dv4[i] = ((const int4*)(dst + bstart))[q];
            atomicAdd(&base_s[sv4[i].x >> SHIFT], 1);
            atomicAdd(&base_s[sv4[i].y >> SHIFT], 1);
            atomicAdd(&base_s[sv4[i].z >> SHIFT], 1);
            atomicAdd(&base_s[sv4[i].w >> SHIFT], 1);
            atomicAdd(&base_d[dv4[i].x >> SHIFT], 1);
            atomicAdd(&base_d[dv4[i].y >> SHIFT], 1);
            atomicAdd(&base_d[dv4[i].z >> SHIFT], 1);
            atomicAdd(&base_d[dv4[i].w >> SHIFT], 1);
        }
    }
    if (have_t) {
        sv_t = src[bstart + (n4 << 2) + t];
        dv_t = dst[bstart + (n4 << 2) + t];
        atomicAdd(&base_s[sv_t >> SHIFT], 1);
        atomicAdd(&base_d[dv_t >> SHIFT], 1);
    }
    __syncthreads();

    // phase 2: dual exclusive scan (thread t owns entries 2t, 2t+1)
    int hd0 = base_d[2*t], hd1 = base_d[2*t+1];
    int hs0 = base_s[2*t], hs1 = base_s[2*t+1];
    int sd = hd0 + hd1, ss = hs0 + hs1;
    int lane = t & 63, wid = t >> 6;
    int id_ = sd, is_ = ss;
#pragma unroll
    for (int off = 1; off < 64; off <<= 1) {
        int vd = __shfl_up(id_, off, 64);
        int vs = __shfl_up(is_, off, 64);
        if (lane >= off) { id_ += vd; is_ += vs; }
    }
    if (lane == 63) { wsA[wid] = id_; wsB[wid] = is_; }
    __syncthreads();
    int wd = 0, ws_ = 0;
    for (int w = 0; w < wid; ++w) { wd += wsA[w]; ws_ += wsB[w]; }
    int excl_d = wd + id_ - sd;
    int excl_s = ws_ + is_ - ss;
    if (hd0 > 0) gbase_d[2*t]   = atomicAdd(&cur_dst[2*t],   hd0);
    if (hd1 > 0) gbase_d[2*t+1] = atomicAdd(&cur_dst[2*t+1], hd1);
    if (hs0 > 0) gbase_s[2*t]   = atomicAdd(&cur_src[2*t],   hs0);
    if (hs1 > 0) gbase_s[2*t+1] = atomicAdd(&cur_src[2*t+1], hs1);
    base_d[2*t] = excl_d;  base_d[2*t+1] = excl_d + hd0;
    base_s[2*t] = excl_s;  base_s[2*t+1] = excl_s + hs0;
    __syncthreads();

    // phase 3: dual scatter into LDS staging; base arrays ARE the cursors
#pragma unroll
    for (int i = 0; i < EPT4; ++i) {
        int q = i * THREADS + t;
        if (q < n4) {
            int ss4[4] = { sv4[i].x, sv4[i].y, sv4[i].z, sv4[i].w };
            int dd4[4] = { dv4[i].x, dv4[i].y, dv4[i].z, dv4[i].w };
#pragma unroll
            for (int k = 0; k < 4; ++k) {
                int s = ss4[k], d = dd4[k];
                int pd = atomicAdd(&base_d[d >> SHIFT], 1);
                st_p[pd] = ((unsigned int)s << SHIFT) | ((unsigned int)d & 255u);
                int ps = atomicAdd(&base_s[s >> SHIFT], 1);
                st_s[ps] = (unsigned char)(s & 255);
            }
        }
    }
    if (have_t) {
        int pd = atomicAdd(&base_d[dv_t >> SHIFT], 1);
        st_p[pd] = ((unsigned int)sv_t << SHIFT) | ((unsigned int)dv_t & 255u);
        int ps = atomicAdd(&base_s[sv_t >> SHIFT], 1);
        st_s[ps] = (unsigned char)(sv_t & 255);
    }
    __syncthreads();

    // phase 3b: coarse slot->bucket tables (one binary search per 16 slots)
    {
        int target = t << 4;
        int lo = 0, hi = NB_MAX;
        while (lo < hi) { int mid = (lo + hi) >> 1; if (base_d[mid] > target) hi = mid; else lo = mid + 1; }
        jb_d[t] = (unsigned short)lo;
        lo = 0; hi = NB_MAX;
        while (lo < hi) { int mid = (lo + hi) >> 1; if (base_s[mid] > target) hi = mid; else lo = mid + 1; }
        jb_s[t] = (unsigned short)lo;
    }
    __syncthreads();

    // phase 4: flush — jb + short monotone advance; coalesced run writes
    for (int j = t; j < bcount; j += THREADS) {
        int b = jb_d[j >> 4];
        while (base_d[b] <= j) ++b;
        int ob = b ? base_d[b - 1] : 0;
        pairs[gbase_d[b] + (j - ob)] = st_p[j];
        int c = jb_s[j >> 4];
        while (base_s[c] <= j) ++c;
        int oc = c ? base_s[c - 1] : 0;
        psrc[gbase_s[c] + (j - oc)] = st_s[j];
    }
}

// ---------------------------------------------------------------------------
// k_count_src: one block per src-bucket. LDS-count out-degrees (256 counters),
// then emit rsq_out and xs = x*ro with fully contiguous writes.
// ---------------------------------------------------------------------------
__global__ __launch_bounds__(THREADS) void k_count_src(
    const unsigned char* __restrict__ psrc, const int* __restrict__ base_src,
    const int* __restrict__ cnt_src, const float* __restrict__ x,
    float* __restrict__ rsq_out, float* __restrict__ xs, int nN)
{
    __shared__ int c[256];
    int t = threadIdx.x, b = blockIdx.x;
    c[t] = 0;
    __syncthreads();
    int start = base_src[b], end = start + cnt_src[b];
    for (int e = start + t; e < end; e += THREADS)
        atomicAdd(&c[psrc[e]], 1);
    __syncthreads();
    int n = (b << SHIFT) + t;
    if (n < nN) {
        int cc = c[t];
        float ro = rsqrtf((float)(cc > 1 ? cc : 1));
        rsq_out[n] = ro;
        const float4* x4 = (const float4*)(x + (size_t)n * 16);
        float4* xs4 = (float4*)(xs + (size_t)n * 16);
#pragma unroll
        for (int k = 0; k < 4; ++k) {
            float4 v = x4[k];
            v.x *= ro; v.y *= ro; v.z *= ro; v.w *= ro;
            xs4[k] = v;
        }
    }
}

// ---------------------------------------------------------------------------
// k_bin_dst: one block per dst-bucket. Pass 1: LDS-count deg_in. Block scan
// -> row_start = bucket_base + local exclusive (bucket-major == node order).
// Write deg_in/rsq_in/row_start contiguously. Pass 2: scatter src ids into
// csr_src via LDS cursors (bucket-local 32KB window stays L2-resident).
// ---------------------------------------------------------------------------
__global__ __launch_bounds__(THREADS) void k_bin_dst(
    const unsigned int* __restrict__ pairs, const int* __restrict__ base_dst,
    const int* __restrict__ cnt_dst, int* __restrict__ deg_in,
    float* __restrict__ rsq_in, int* __restrict__ row_start,
    int* __restrict__ csr_src, int nN)
{
    __shared__ int c[256];
    __shared__ int cur[256];
    __shared__ int wsum[4];
    int t = threadIdx.x, b = blockIdx.x;
    c[t] = 0;
    __syncthreads();
    int start = base_dst[b], end = start + cnt_dst[b];
    for (int e = start + t; e < end; e += THREADS)
        atomicAdd(&c[pairs[e] & 255u], 1);
    __syncthreads();
    int cc = c[t];
    int lane = t & 63, wid = t >> 6;
    int incl = cc;
#pragma unroll
    for (int off = 1; off < 64; off <<= 1) {
        int v = __shfl_up(incl, off, 64);
        if (lane >= off) incl += v;
    }
    if (lane == 63) wsum[wid] = incl;
    __syncthreads();
    int woff = 0;
    for (int w = 0; w < wid; ++w) woff += wsum[w];
    int rs = start + woff + incl - cc;
    cur[t] = rs;
    int n = (b << SHIFT) + t;
    if (n < nN) {
        deg_in[n] = cc;
        rsq_in[n] = rsqrtf((float)(cc > 1 ? cc : 1));
        row_start[n] = rs;
    }
    __syncthreads();
    for (int e = start + t; e < end; e += THREADS) {
        unsigned int pr = pairs[e];
        int pos = atomicAdd(&cur[pr & 255u], 1);
        csr_src[pos] = (int)(pr >> SHIFT);
    }
}

// ---------------------------------------------------------------------------
// k_agg1: gather-side aggregation, 4 lanes per node; unroll-8 keeps 8
// independent gathers in flight to hide L2/L3 latency.
// ---------------------------------------------------------------------------
__global__ void k_agg1(const int* __restrict__ row_start, const int* __restrict__ deg_in,
                       const int* __restrict__ csr_src, const float* __restrict__ feat,
                       float* __restrict__ agg, int nN) {
    int tid = blockIdx.x * blockDim.x + threadIdx.x;
    int n = tid >> 2, q = tid & 3;
    if (n >= nN) return;
    int row = row_start[n], deg = deg_in[n];
    const float* fb = feat + q * 4;
    float4 acc = make_float4(0.f, 0.f, 0.f, 0.f);
    float4 acc2 = make_float4(0.f, 0.f, 0.f, 0.f);
    int i = 0;
    for (; i + 8 <= deg; i += 8) {
        int s[8];
#pragma unroll
        for (int k = 0; k < 8; ++k) s[k] = csr_src[row + i + k];
        float4 v[8];
#pragma unroll
        for (int k = 0; k < 8; ++k) v[k] = *(const float4*)(fb + (size_t)s[k] * 16);
        acc.x  += v[0].x + v[1].x + v[2].x + v[3].x;
        acc.y  += v[0].y + v[1].y + v[2].y + v[3].y;
        acc.z  += v[0].z + v[1].z + v[2].z + v[3].z;
        acc.w  += v[0].w + v[1].w + v[2].w + v[3].w;
        acc2.x += v[4].x + v[5].x + v[6].x + v[7].x;
        acc2.y += v[4].y + v[5].y + v[6].y + v[7].y;
        acc2.z += v[4].z + v[5].z + v[6].z + v[7].z;
        acc2.w += v[4].w + v[5].w + v[6].w + v[7].w;
    }
    for (; i + 4 <= deg; i += 4) {
        int s0 = csr_src[row + i];
        int s1 = csr_src[row + i + 1];
        int s2 = csr_src[row + i + 2];
        int s3 = csr_src[row + i + 3];
        float4 v0 = *(const float4*)(fb + (size_t)s0 * 16);
        float4 v1 = *(const float4*)(fb + (size_t)s1 * 16);
        float4 v2 = *(const float4*)(fb + (size_t)s2 * 16);
        float4 v3 = *(const float4*)(fb + (size_t)s3 * 16);
        acc.x += v0.x + v1.x + v2.x + v3.x;
        acc.y += v0.y + v1.y + v2.y + v3.y;
        acc.z += v0.z + v1.z + v2.z + v3.z;
        acc.w += v0.w + v1.w + v2.w + v3.w;
    }
    for (; i < deg; ++i) {
        int s0 = csr_src[row + i];
        float4 v0 = *(const float4*)(fb + (size_t)s0 * 16);
        acc.x += v0.x; acc.y += v0.y; acc.z += v0.z; acc.w += v0.w;
    }
    acc.x += acc2.x; acc.y += acc2.y; acc.z += acc2.z; acc.w += acc2.w;
    ((float4*)agg)[(size_t)n * 4 + q] = acc;
}

// ---------------------------------------------------------------------------
// k_mlp: chunked; tanh via native v_exp_f32 + v_rcp_f32 (no libm path):
//   tanh(v) = 1 - 2 / (exp(2v) + 1)
// ---------------------------------------------------------------------------
__global__ __launch_bounds__(THREADS) void k_mlp(
    const float* __restrict__ agg1, const float* __restrict__ rsq_in,
    const float* __restrict__ rsq_out, const float* __restrict__ w1,
    const float* __restrict__ b1, const float* __restrict__ w2,
    float* __restrict__ z, int nN)
{
    int n = blockIdx.x * blockDim.x + threadIdx.x;
    if (n >= nN) return;
    float ri = rsq_in[n];
    const float4* a4 = (const float4*)(agg1 + (size_t)n * 16);
    float t[16];
#pragma unroll
    for (int k = 0; k < 4; ++k) {
        float4 v = a4[k];
        t[4*k+0] = v.x * ri; t[4*k+1] = v.y * ri;
        t[4*k+2] = v.z * ri; t[4*k+3] = v.w * ri;
    }
    float u[16];
#pragma unroll
    for (int o = 0; o < 16; ++o) u[o] = 0.f;
#pragma unroll
    for (int c = 0; c < 4; ++c) {
        float yv[16];
#pragma unroll
        for (int jj = 0; jj < 16; ++jj) yv[jj] = b1[c*16 + jj];
#pragma unroll
        for (int i = 0; i < 16; ++i) {
            float ti = t[i];
#pragma unroll
            for (int jj = 0; jj < 16; ++jj)
                yv[jj] = fmaf(ti, w1[i*64 + c*16 + jj], yv[jj]);
        }
#pragma unroll
        for (int jj = 0; jj < 16; ++jj) {
            float e = __expf(2.f * yv[jj]);
            yv[jj] = 1.f - 2.f * __builtin_amdgcn_rcpf(e + 1.f);
        }
#pragma unroll
        for (int jj = 0; jj < 16; ++jj) {
            float yj = yv[jj];
#pragma unroll
            for (int o = 0; o < 16; ++o)
                u[o] = fmaf(yj, w2[(c*16 + jj)*16 + o], u[o]);
        }
    }
    float ro = rsq_out[n];
    float4* z4 = (float4*)(z + (size_t)n * 16);
#pragma unroll
    for (int k = 0; k < 4; ++k)
        z4[k] = make_float4(u[4*k+0]*ro, u[4*k+1]*ro, u[4*k+2]*ro, u[4*k+3]*ro);
}

// ---------------------------------------------------------------------------
// k_agg2: gather + fused epilogue (ri, b2, symplectic permute via shfl_xor 2).
// ---------------------------------------------------------------------------
__global__ void k_agg2(const int* __restrict__ row_start, const int* __restrict__ deg_in,
                       const int* __restrict__ csr_src, const float* __restrict__ feat,
                       const float* __restrict__ rsq_in, const float* __restrict__ b2,
                       float* __restrict__ out, int nN) {
    int tid = blockIdx.x * blockDim.x + threadIdx.x;
    int n = tid >> 2, q = tid & 3;
    if (n >= nN) return;
    int row = row_start[n], deg = deg_in[n];
    const float* fb = feat + q * 4;
    float4 acc = make_float4(0.f, 0.f, 0.f, 0.f);
    float4 acc2 = make_float4(0.f, 0.f, 0.f, 0.f);
    int i = 0;
    for (; i + 8 <= deg; i += 8) {
        int s[8];
#pragma unroll
        for (int k = 0; k < 8; ++k) s[k] = csr_src[row + i + k];
        float4 v[8];
#pragma unroll
        for (int k = 0; k < 8; ++k) v[k] = *(const float4*)(fb + (size_t)s[k] * 16);
        acc.x  += v[0].x + v[1].x + v[2].x + v[3].x;
        acc.y  += v[0].y + v[1].y + v[2].y + v[3].y;
        acc.z  += v[0].z + v[1].z + v[2].z + v[3].z;
        acc.w  += v[0].w + v[1].w + v[2].w + v[3].w;
        acc2.x += v[4].x + v[5].x + v[6].x + v[7].x;
        acc2.y += v[4].y + v[5].y + v[6].y + v[7].y;
        acc2.z += v[4].z + v[5].z + v[6].z + v[7].z;
        acc2.w += v[4].w + v[5].w + v[6].w + v[7].w;
    }
    for (; i + 4 <= deg; i += 4) {
        int s0 = csr_src[row + i];
        int s1 = csr_src[row + i + 1];
        int s2 = csr_src[row + i + 2];
        int s3 = csr_src[row + i + 3];
        float4 v0 = *(const float4*)(fb + (size_t)s0 * 16);
        float4 v1 = *(const float4*)(fb + (size_t)s1 * 16);
        float4 v2 = *(const float4*)(fb + (size_t)s2 * 16);
        float4 v3 = *(const float4*)(fb + (size_t)s3 * 16);
        acc.x += v0.x + v1.x + v2.x + v3.x;
        acc.y += v0.y + v1.y + v2.y + v3.y;
        acc.z += v0.z + v1.z + v2.z + v3.z;
        acc.w += v0.w + v1.w + v2.w + v3.w;
    }
    for (; i < deg; ++i) {
        int s0 = csr_src[row + i];
        float4 v0 = *(const float4*)(fb + (size_t)s0 * 16);
        acc.x += v0.x; acc.y += v0.y; acc.z += v0.z; acc.w += v0.w;
    }
    acc.x += acc2.x; acc.y += acc2.y; acc.z += acc2.z; acc.w += acc2.w;
    float ri = rsq_in[n];
    float4 bq = *(const float4*)(b2 + q * 4);
    float4 g = make_float4(fmaf(acc.x, ri, bq.x), fmaf(acc.y, ri, bq.y),
                           fmaf(acc.z, ri, bq.z), fmaf(acc.w, ri, bq.w));
    float4 p;
    p.x = __shfl_xor(g.x, 2, 64);
    p.y = __shfl_xor(g.y, 2, 64);
    p.z = __shfl_xor(g.z, 2, 64);
    p.w = __shfl_xor(g.w, 2, 64);
    float sgn = (q < 2) ? 1.f : -1.f;
    ((float4*)out)[(size_t)n * 4 + q] =
        make_float4(sgn * p.x, sgn * p.y, sgn * p.z, sgn * p.w);
}

extern "C" void kernel_launch(void* const* d_in, const int* in_sizes, int n_in,
                              void* d_out, int out_size, void* d_ws, size_t ws_size,
                              hipStream_t stream) {
    const float* x  = (const float*)d_in[0];
    const int*   src = (const int*)d_in[1];
    const int*   dst = (const int*)d_in[2];
    const float* w1 = (const float*)d_in[3];
    const float* b1 = (const float*)d_in[4];
    const float* w2 = (const float*)d_in[5];
    const float* b2 = (const float*)d_in[6];
    float* out = (float*)d_out;

    const int nN = in_sizes[0] / 16;
    const int nE = in_sizes[1];
    const int NB = (nN + (1 << SHIFT) - 1) >> SHIFT;   // 391 for nN=100k

    // Workspace carve-up (256B aligned). ~37 MB.
    char* ws = (char*)d_ws;
    size_t off = 0;
    auto carve = [&](size_t bytes) -> void* {
        void* p = ws + off;
        off += (bytes + 255) & ~(size_t)255;
        return p;
    };
    int* cnt_src = (int*)carve((size_t)2 * NB_MAX * sizeof(int));  // [cnt_src|cnt_dst]
    int* cnt_dst = cnt_src + NB_MAX;
    int* base_src = (int*)carve((size_t)NB_MAX * sizeof(int));
    int* cur_src  = (int*)carve((size_t)NB_MAX * sizeof(int));
    int* base_dst = (int*)carve((size_t)NB_MAX * sizeof(int));
    int* cur_dst  = (int*)carve((size_t)NB_MAX * sizeof(int));
    float* rsq_out  = (float*)carve((size_t)nN * sizeof(float));
    float* rsq_in   = (float*)carve((size_t)nN * sizeof(float));
    int*   row_start = (int*)carve((size_t)nN * sizeof(int));
    int*   deg_in    = (int*)carve((size_t)nN * sizeof(int));
    float* xs   = (float*)carve((size_t)nN * 16 * sizeof(float)); // xs, later z
    int*   csr_src = (int*)carve((size_t)nE * sizeof(int));
    unsigned char* psrc = (unsigned char*)carve((size_t)nE);
    // pairs (dead after k_bin_dst) aliases agg1 (live from k_agg1 on)
    size_t un_sz = (size_t)nE * 4 > (size_t)nN * 64 ? (size_t)nE * 4 : (size_t)nN * 64;
    void* un = carve(un_sz);
    unsigned int* pairs = (unsigned int*)un;
    float* agg1 = (float*)un;

    const int node_blocks = (nN + THREADS - 1) / THREADS;
    const int quad_blocks = (4 * nN + THREADS - 1) / THREADS;
    const int batch_blocks = (nE + BATCH - 1) / BATCH;

    // 1. zero bucket counts (4 KB)
    hipMemsetAsync(cnt_src, 0, (size_t)2 * NB_MAX * sizeof(int), stream);
    // 2. bucket histograms (src & dst) — no per-node atomics
    k_hist<<<512, THREADS, 0, stream>>>(src, dst, cnt_src, cnt_dst, nE);
    // 3. scan both
    k_bscan<<<1, THREADS, 0, stream>>>(cnt_src, cnt_dst, base_src, cur_src, base_dst, cur_dst);
    // 4. fused bucket-grouping of edges by dst AND src (one edge read pass)
    k_bucket_both<<<batch_blocks, THREADS, 0, stream>>>(src, dst, cur_dst, cur_src,
                                                        pairs, psrc, nE);
    // 5. out-degree counting + rsq_out + xs (all contiguous writes)
    k_count_src<<<NB, THREADS, 0, stream>>>(psrc, base_src, cnt_src, x, rsq_out, xs, nN);
    // 6. in-degree, rsq_in, row_start (free global scan), CSR scatter via LDS cursors
    k_bin_dst<<<NB, THREADS, 0, stream>>>(pairs, base_dst, cnt_dst, deg_in, rsq_in,
                                          row_start, csr_src, nN);
    // 7. layer-1 aggregation (gather-side, register accumulate)
    k_agg1<<<quad_blocks, THREADS, 0, stream>>>(row_start, deg_in, csr_src, xs, agg1, nN);
    // 8. fused MLP (W2 hoisted); writes z into xs
    k_mlp<<<node_blocks, THREADS, 0, stream>>>(agg1, rsq_in, rsq_out, w1, b1, w2, xs, nN);
    // 9. layer-2 aggregation + fused epilogue
    k_agg2<<<quad_blocks, THREADS, 0, stream>>>(row_start, deg_in, csr_src, xs,
                                                rsq_in, b2, out, nN);
}